// Round 10
// baseline (197.444 us; speedup 1.0000x reference)
//
#include <hip/hip_runtime.h>
#include <math.h>

#define B_ 8
#define C_ 512
#define S_ 1024
#define HD 64
#define NHEADS 8
#define NGROUPS 8
#define DT_STEP 0.1f
#define EPS_GN 1e-5f
#define LOG2E 1.4426950408889634f

typedef __attribute__((ext_vector_type(8))) short bf16x8;
typedef __attribute__((ext_vector_type(4))) float f32x4;
typedef __attribute__((ext_vector_type(8))) unsigned short ushort8;
typedef __attribute__((ext_vector_type(4))) unsigned short ushort4_t;

static __device__ __forceinline__ unsigned short f2bf(float f) {     // RNE (cold paths)
  unsigned int u = __builtin_bit_cast(unsigned int, f);
  u += 0x7fff + ((u >> 16) & 1);
  return (unsigned short)(u >> 16);
}

static __device__ __forceinline__ unsigned short f2bf_fast(float f) { // round-half-up (hot paths)
  unsigned int u = __builtin_bit_cast(unsigned int, f);
  return (unsigned short)((u + 0x8000u) >> 16);
}

static __device__ __forceinline__ float bf2f(unsigned short u) {
  unsigned int t = ((unsigned int)u) << 16;
  return __builtin_bit_cast(float, t);
}

static __device__ __forceinline__ float exp2_raw(float x) {
  return __builtin_amdgcn_exp2f(x);    // single v_exp_f32
}

static __device__ __forceinline__ float fast_tanh(float x) {
  float xc = fminf(fmaxf(x, -15.f), 15.f);
  float e = exp2_raw(xc * (2.0f * LOG2E));
  return (e - 1.f) / (e + 1.f);
}

// ---------------- prep: cast fp32 weights -> bf16  +  GroupNorm partial sums ----------------
// qkv_w: row-major [o][c] bf16 (consumed by gemm_nt_core LDS staging)
// inl_w / proj_w: SLAB-INTERLEAVED layout W2[(c>>5)*16384 + o*32 + (c&31)]
//   -> each 32-k slab is a contiguous 32KB block [512 o][32 k]; the chain kernel
//      stages two consecutive slabs (64KB) per round with fully-coalesced loads.
__global__ __launch_bounds__(256) void prep_kernel(
    const float* __restrict__ a, const float* __restrict__ b, const float* __restrict__ c,
    unsigned short* __restrict__ A, unsigned short* __restrict__ B, unsigned short* __restrict__ C,
    const float* __restrict__ x, float* __restrict__ gpart) {
  int bid = blockIdx.x;
  int tid = threadIdx.x;
  if (bid < 384) {                     // qkv weights: plain row-major cast
    int off = bid * 2048;
    int i = off + tid * 8;
    f32x4 v0 = *(const f32x4*)(a + i);
    f32x4 v1 = *(const f32x4*)(a + i + 4);
    ushort8 o;
    o[0] = f2bf(v0[0]); o[1] = f2bf(v0[1]); o[2] = f2bf(v0[2]); o[3] = f2bf(v0[3]);
    o[4] = f2bf(v1[0]); o[5] = f2bf(v1[1]); o[6] = f2bf(v1[2]); o[7] = f2bf(v1[3]);
    *(ushort8*)(A + i) = o;
    return;
  }
  if (bid < 640) {                     // inl/proj weights: slab-interleaved cast
    const float* src; unsigned short* dst; int off;
    if (bid < 512) { src = b; dst = B; off = (bid - 384) * 2048; }
    else { src = c; dst = C; off = (bid - 512) * 2048; }
    int i = off + tid * 8;
    f32x4 v0 = *(const f32x4*)(src + i);
    f32x4 v1 = *(const f32x4*)(src + i + 4);
    ushort8 o;
    o[0] = f2bf(v0[0]); o[1] = f2bf(v0[1]); o[2] = f2bf(v0[2]); o[3] = f2bf(v0[3]);
    o[4] = f2bf(v1[0]); o[5] = f2bf(v1[1]); o[6] = f2bf(v1[2]); o[7] = f2bf(v1[3]);
    int orow = i >> 9, cbase = i & 511;
    int dsti = (cbase >> 5) * 16384 + orow * 32 + (cbase & 31);
    *(ushort8*)(dst + dsti) = o;
    return;
  }
  int sbid = bid - 640;
  int bg = sbid >> 3, chunk = sbid & 7;
  const float* xp = x + (size_t)bg * 65536 + (size_t)chunk * 8192;
  float sum = 0.f, sq = 0.f;
  #pragma unroll
  for (int i = 0; i < 8; ++i) {
    f32x4 v = *(const f32x4*)(xp + i * 1024 + tid * 4);
    sum += v[0] + v[1] + v[2] + v[3];
    sq += v[0]*v[0] + v[1]*v[1] + v[2]*v[2] + v[3]*v[3];
  }
  #pragma unroll
  for (int off = 32; off >= 1; off >>= 1) {
    sum += __shfl_xor(sum, off, 64);
    sq  += __shfl_xor(sq, off, 64);
  }
  __shared__ float s1[4], s2[4];
  int wave = tid >> 6, lane = tid & 63;
  if (lane == 0) { s1[wave] = sum; s2[wave] = sq; }
  __syncthreads();
  if (tid == 0) {
    float S = s1[0] + s1[1] + s1[2] + s1[3];
    float Q = s2[0] + s2[1] + s2[2] + s2[3];
    gpart[bg * 16 + chunk * 2] = S;
    gpart[bg * 16 + chunk * 2 + 1] = Q;
  }
}

// ---------------- GroupNorm pass 2: normalize + transpose to h_t[B,S,C] bf16 ----------------
__global__ __launch_bounds__(256) void gn_apply_t(
    const float* __restrict__ x, const float* __restrict__ gpart,
    const float* __restrict__ scale, const float* __restrict__ bias,
    unsigned short* __restrict__ h_t) {
  int bid = blockIdx.x;
  int bg = bid >> 4, st = bid & 15;
  int b = bg >> 3, g = bg & 7;
  float S = 0.f, Q = 0.f;
  #pragma unroll
  for (int i = 0; i < 8; ++i) {
    S += gpart[bg * 16 + i * 2];
    Q += gpart[bg * 16 + i * 2 + 1];
  }
  float mean = S / 65536.f;
  float var = Q / 65536.f - mean * mean;
  float inv = rsqrtf(var + EPS_GN);

  int tid = threadIdx.x;
  int sl = tid >> 2;
  int cq = (tid & 3) * 16;
  float sA[16], sB[16];
  #pragma unroll
  for (int u = 0; u < 16; ++u) {
    float scv = scale[g * 64 + cq + u];
    sA[u] = inv * scv;
    sB[u] = bias[g * 64 + cq + u] - mean * inv * scv;
  }

  const float* xp = x + ((size_t)b * C_ + (size_t)g * 64) * S_;
  __shared__ float tile[64][65];
  #pragma unroll
  for (int it = 0; it < 16; ++it) {
    int lin = it * 256 + tid;
    int c = lin >> 6, s = lin & 63;
    tile[c][s] = xp[(size_t)c * S_ + st * 64 + s];
  }
  __syncthreads();
  unsigned short vals[16];
  #pragma unroll
  for (int u = 0; u < 16; ++u)
    vals[u] = f2bf_fast(tile[cq + u][sl] * sA[u] + sB[u]);
  unsigned short* dst = h_t + ((size_t)b * S_ + st * 64 + sl) * C_ + g * 64 + cq;
  ushort8 lo, hi;
  #pragma unroll
  for (int u = 0; u < 8; ++u) { lo[u] = vals[u]; hi[u] = vals[u + 8]; }
  *(ushort8*)dst = lo;
  *(ushort8*)(dst + 8) = hi;
}

// ---------------- NT GEMM core, register-prefetch pipelined staging ----------------
// C[MB,NB] = A[MB,512] * B[NB,512]^T ; next k-slab loads issue during MFMA phase.
template<int MB, int NB, int WMG, int WNG>
__device__ __forceinline__ void gemm_nt_core(
    const unsigned short* __restrict__ Ab,
    const unsigned short* __restrict__ Bb,
    unsigned short* ldsA, unsigned short* ldsB,
    f32x4* acc) {
  constexpr int TI = (MB / WMG) / 16;
  constexpr int TJ = (NB / WNG) / 16;
  constexpr int NQA = MB * 4 / 256;          // 16B chunks per thread (A)
  constexpr int NQB = NB * 4 / 256;
  const int K = 512;
  const int tid = threadIdx.x;
  const int w = tid >> 6, lane = tid & 63, quad = lane >> 4, l15 = lane & 15;
  const int wm = (WNG == 1) ? w : ((WMG == 1) ? 0 : (w >> 1));
  const int wn = (WNG == 1) ? 0 : ((WMG == 1) ? w : (w & 1));

  ushort8 apf[NQA], bpf[NQB];
  #pragma unroll
  for (int q = 0; q < NQA; ++q) {
    int c = q * 256 + tid;
    apf[q] = *(const ushort8*)(Ab + (size_t)(c >> 2) * K + (c & 3) * 8);
  }
  #pragma unroll
  for (int q = 0; q < NQB; ++q) {
    int c = q * 256 + tid;
    bpf[q] = *(const ushort8*)(Bb + (size_t)(c >> 2) * K + (c & 3) * 8);
  }

  for (int k0 = 0; k0 < K; k0 += 32) {
    __syncthreads();                         // prior slab consumed
    #pragma unroll
    for (int q = 0; q < NQA; ++q) {
      int c = q * 256 + tid;
      *(ushort8*)(ldsA + c * 8) = apf[q];
    }
    #pragma unroll
    for (int q = 0; q < NQB; ++q) {
      int c = q * 256 + tid;
      *(ushort8*)(ldsB + c * 8) = bpf[q];
    }
    __syncthreads();
    if (k0 + 32 < K) {                       // issue next-slab loads; waited next iter
      #pragma unroll
      for (int q = 0; q < NQA; ++q) {
        int c = q * 256 + tid;
        apf[q] = *(const ushort8*)(Ab + (size_t)(c >> 2) * K + k0 + 32 + (c & 3) * 8);
      }
      #pragma unroll
      for (int q = 0; q < NQB; ++q) {
        int c = q * 256 + tid;
        bpf[q] = *(const ushort8*)(Bb + (size_t)(c >> 2) * K + k0 + 32 + (c & 3) * 8);
      }
    }
    bf16x8 af[TI], bfr[TJ];
    #pragma unroll
    for (int i = 0; i < TI; ++i)
      af[i] = *(const bf16x8*)(ldsA + (wm * (MB / WMG) + i * 16 + l15) * 32 + quad * 8);
    #pragma unroll
    for (int j = 0; j < TJ; ++j)
      bfr[j] = *(const bf16x8*)(ldsB + (wn * (NB / WNG) + j * 16 + l15) * 32 + quad * 8);
    #pragma unroll
    for (int i = 0; i < TI; ++i)
      #pragma unroll
      for (int j = 0; j < TJ; ++j)
        acc[i * TJ + j] = __builtin_amdgcn_mfma_f32_16x16x32_bf16(af[i], bfr[j], acc[i * TJ + j], 0, 0, 0);
  }
}

// ---------------- QKV GEMM: W_bf[1536,512] x h_t[b][1024,512]^T ----------------
__global__ __launch_bounds__(256) void gemm_qkv_mfma(
    const unsigned short* __restrict__ Wbf, const unsigned short* __restrict__ h_t,
    const float* __restrict__ bias,
    unsigned short* __restrict__ Qt, unsigned short* __restrict__ Kt,
    unsigned short* __restrict__ Vt) {
  __shared__ __align__(16) unsigned short ldsA[128 * 32];
  __shared__ __align__(16) unsigned short ldsB[128 * 32];
  int b = blockIdx.z;
  int bm = blockIdx.y * 128, bn = blockIdx.x * 128;
  f32x4 acc[16];
  #pragma unroll
  for (int t = 0; t < 16; ++t) acc[t] = (f32x4){0.f, 0.f, 0.f, 0.f};
  gemm_nt_core<128, 128, 2, 2>(Wbf + (size_t)bm * 512,
                               h_t + ((size_t)b * S_ + bn) * 512, ldsA, ldsB, acc);
  int tid = threadIdx.x, w = tid >> 6, lane = tid & 63, quad = lane >> 4, l15 = lane & 15;
  int wm = w >> 1, wn = w & 1;
  int tensor = bm >> 9;
  float qscale = (tensor == 0) ? 0.125f * LOG2E : 1.0f;
  #pragma unroll
  for (int i = 0; i < 4; ++i) {
    #pragma unroll
    for (int j = 0; j < 4; ++j) {
      int m0 = bm + wm * 64 + i * 16 + quad * 4;
      int ng = bn + wn * 64 + j * 16 + l15;
      f32x4 v = acc[i * 4 + j];
      if (tensor < 2) {
        int head = (m0 >> 6) & 7, d0 = m0 & 63;
        ushort4_t pk;
        #pragma unroll
        for (int r = 0; r < 4; ++r) pk[r] = f2bf((v[r] + bias[m0 + r]) * qscale);
        unsigned short* dst = (tensor ? Kt : Qt) +
            (((size_t)(b * 8 + head) * S_ + ng) * 64 + d0);
        *(ushort4_t*)dst = pk;
      } else {
        #pragma unroll
        for (int r = 0; r < 4; ++r)
          Vt[(size_t)b * (C_ * S_) + (size_t)(m0 - 1024 + r) * S_ + ng] = f2bf(v[r] + bias[m0 + r]);
      }
    }
  }
}

// ---------------- Flash attention: transposed scores, 2 q-groups/wave, reg-prefetched K/V ----------------
// grid 512: bid = sblk*64 + (b*8+n); 4 waves x 32 q-rows (2 groups of 16)
__global__ __launch_bounds__(256) void attn_mfma(
    const unsigned short* __restrict__ Qt,   // [B][NH][S][HD] (pre-scaled, incl log2e)
    const unsigned short* __restrict__ Kt,
    const unsigned short* __restrict__ Vt,   // [B][C][S]
    unsigned short* __restrict__ hflat_bf) { // [B][S][C] bf16
  int tid = threadIdx.x, wave = tid >> 6, lane = tid & 63;
  int quad = lane >> 4, l15 = lane & 15;
  int bid = blockIdx.x;
  int bn = bid & 63, sblk = bid >> 6, b = bn >> 3, n = bn & 7;
  int s0w = sblk * 128 + wave * 32;

  __shared__ unsigned short k_lds[64][72];
  __shared__ unsigned short v_lds[64][72];
  __shared__ unsigned short p_lds[4][2][16][72];  // [wave][group][s][t], A-layout

  const unsigned short* Kb = Kt + ((size_t)(b * 8 + n)) * S_ * 64;
  const unsigned short* Vb = Vt + ((size_t)b * C_ + n * 64) * S_;

  bf16x8 qa[2][2];
  #pragma unroll
  for (int g = 0; g < 2; ++g) {
    const unsigned short* Qb = Qt + (((size_t)(b * 8 + n)) * S_ + s0w + g * 16 + l15) * 64;
    qa[g][0] = *(const bf16x8*)(Qb + quad * 8);
    qa[g][1] = *(const bf16x8*)(Qb + 32 + quad * 8);
  }

  bf16x8 ones;
  #pragma unroll
  for (int j = 0; j < 8; ++j) ones[j] = (short)0x3F80;

  f32x4 o_acc[2][4];
  f32x4 l_acc[2];
  #pragma unroll
  for (int g = 0; g < 2; ++g) {
    l_acc[g] = (f32x4){0.f, 0.f, 0.f, 0.f};
    #pragma unroll
    for (int dc = 0; dc < 4; ++dc) o_acc[g][dc] = (f32x4){0.f, 0.f, 0.f, 0.f};
  }

  int row0 = tid >> 3, c80 = (tid & 7) * 8;
  int row1 = (tid + 256) >> 3, c81 = c80;

  ushort8 kreg[2], vreg[2];
  kreg[0] = *(const ushort8*)(Kb + (size_t)row0 * 64 + c80);
  kreg[1] = *(const ushort8*)(Kb + (size_t)row1 * 64 + c81);
  vreg[0] = *(const ushort8*)(Vb + (size_t)row0 * S_ + c80);
  vreg[1] = *(const ushort8*)(Vb + (size_t)row1 * S_ + c81);

  for (int t0 = 0; t0 < S_; t0 += 64) {
    __syncthreads();
    *(ushort8*)&k_lds[row0][c80] = kreg[0];
    *(ushort8*)&k_lds[row1][c81] = kreg[1];
    *(ushort8*)&v_lds[row0][c80] = vreg[0];
    *(ushort8*)&v_lds[row1][c81] = vreg[1];
    __syncthreads();
    if (t0 + 64 < S_) {
      int t1 = t0 + 64;
      kreg[0] = *(const ushort8*)(Kb + (size_t)(t1 + row0) * 64 + c80);
      kreg[1] = *(const ushort8*)(Kb + (size_t)(t1 + row1) * 64 + c81);
      vreg[0] = *(const ushort8*)(Vb + (size_t)row0 * S_ + t1 + c80);
      vreg[1] = *(const ushort8*)(Vb + (size_t)row1 * S_ + t1 + c81);
    }

    // Transposed scores: St[t][s] = sum_d K[t][d] Q[s][d]
    f32x4 sc[2][4];
    #pragma unroll
    for (int tc = 0; tc < 4; ++tc) {
      bf16x8 kb0 = *(const bf16x8*)&k_lds[tc * 16 + l15][quad * 8];
      bf16x8 kb1 = *(const bf16x8*)&k_lds[tc * 16 + l15][32 + quad * 8];
      #pragma unroll
      for (int g = 0; g < 2; ++g) {
        f32x4 c = {0.f, 0.f, 0.f, 0.f};
        c = __builtin_amdgcn_mfma_f32_16x16x32_bf16(kb0, qa[g][0], c, 0, 0, 0);
        sc[g][tc] = __builtin_amdgcn_mfma_f32_16x16x32_bf16(kb1, qa[g][1], c, 0, 0, 0);
      }
    }

    // exp -> P[s][t] in LDS via contiguous b64 writes
    #pragma unroll
    for (int g = 0; g < 2; ++g)
      #pragma unroll
      for (int tc = 0; tc < 4; ++tc) {
        ushort4_t p4;
        #pragma unroll
        for (int r = 0; r < 4; ++r) p4[r] = f2bf_fast(exp2_raw(sc[g][tc][r]));
        *(ushort4_t*)&p_lds[wave][g][l15][tc * 16 + quad * 4] = p4;
      }

    bf16x8 pa[2][2];
    #pragma unroll
    for (int g = 0; g < 2; ++g) {
      pa[g][0] = *(const bf16x8*)&p_lds[wave][g][l15][quad * 8];
      pa[g][1] = *(const bf16x8*)&p_lds[wave][g][l15][32 + quad * 8];
      l_acc[g] = __builtin_amdgcn_mfma_f32_16x16x32_bf16(pa[g][0], ones, l_acc[g], 0, 0, 0);
      l_acc[g] = __builtin_amdgcn_mfma_f32_16x16x32_bf16(pa[g][1], ones, l_acc[g], 0, 0, 0);
    }
    #pragma unroll
    for (int dc = 0; dc < 4; ++dc) {
      bf16x8 vb0 = *(const bf16x8*)&v_lds[dc * 16 + l15][quad * 8];
      bf16x8 vb1 = *(const bf16x8*)&v_lds[dc * 16 + l15][32 + quad * 8];
      #pragma unroll
      for (int g = 0; g < 2; ++g) {
        o_acc[g][dc] = __builtin_amdgcn_mfma_f32_16x16x32_bf16(pa[g][0], vb0, o_acc[g][dc], 0, 0, 0);
        o_acc[g][dc] = __builtin_amdgcn_mfma_f32_16x16x32_bf16(pa[g][1], vb1, o_acc[g][dc], 0, 0, 0);
      }
    }
  }

  #pragma unroll
  for (int g = 0; g < 2; ++g) {
    float inv_l[4];
    #pragma unroll
    for (int r = 0; r < 4; ++r) inv_l[r] = 1.f / l_acc[g][r];
    #pragma unroll
    for (int dc = 0; dc < 4; ++dc) {
      #pragma unroll
      for (int r = 0; r < 4; ++r) {
        int s = s0w + g * 16 + quad * 4 + r;
        size_t idx = ((size_t)b * S_ + s) * C_ + n * 64 + dc * 16 + l15;
        hflat_bf[idx] = f2bf_fast(o_acc[g][dc][r] * inv_l[r]);
      }
    }
  }
}

// ---------------- Fused INL x3 + proj + residual: h rows + W slabs in LDS ----------------
// 256 blocks x 1024 threads (16 waves = 4/SIMD). Block owns 32 rows of h in LDS.
// Rounds 3-9 lesson: register-ring pipelines are either sunk to depth-0 (latency-bound,
// 44us) or spill when pinned. The ONE proven pipelining mechanism in this file is
// gemm_nt_core's barrier-structured LDS staging: loads issued after barrier B can't
// cross __syncthreads (memory fence), and their wait lands at the LDS-write after the
// NEXT barrier A -- a full compute phase of in-flight distance, no forced liveness.
// Apply it to W: per round (K=64), stage 64KB (2 slabs) into w_lds via regs; consume
// via ds_read (2-way banks with pad 72 = free). W-load latency overlaps consume.
__global__ __launch_bounds__(1024, 4) void inl_proj_chain(
    const unsigned short* __restrict__ hbf,   // [B*S][512] bf16 (attn out rows)
    const unsigned short* __restrict__ Wi2,   // inl W, slab-interleaved [16][512][32]
    const unsigned short* __restrict__ Wp2,   // proj W, slab-interleaved
    const float* __restrict__ ib, const float* __restrict__ pb,
    const float* __restrict__ x, float* __restrict__ Out) {
  __shared__ __align__(16) unsigned short h_lds[32][520];   // 33,280 B; stride 1040B -> 2-way banks
  __shared__ __align__(16) unsigned short w_lds[512][72];   // 73,728 B; stride 144B -> 2-way banks

  int tid = threadIdx.x;
  int wave = tid >> 6, lane = tid & 63, quad = lane >> 4, l15 = lane & 15;
  int wo = wave * 32;                        // this wave's 32 output channels
  int bid = blockIdx.x;
  int b = bid >> 5, s0 = (bid & 31) * 32;    // 32 blocks per batch image

  // h row loads + stage of round 0 W issue together up front
  const unsigned short* hsrc = hbf + (size_t)bid * 16384;
  ushort8 hv0 = *(const ushort8*)(hsrc + (size_t)tid * 8);
  ushort8 hv1 = *(const ushort8*)(hsrc + (size_t)(1024 + tid) * 8);

  float bi0 = ib[wo + l15], bi1 = ib[wo + 16 + l15];
  float bp0 = pb[wo + l15], bp1 = pb[wo + 16 + l15];

  // staging maps: chunk i = q*1024+tid covers shorts [i*8, i*8+8) of the 64KB region;
  // dest row (i>>2)&511, col (i>>11)*32 + (i&3)*8  (q=0,1 -> slab 0; q=2,3 -> slab 1)
  const int sr = tid >> 2, sc = (tid & 3) * 8;
  ushort8 st0, st1, st2, st3;

#define LDW_(g) { \
    const unsigned short* p_ = (((g) < 24) ? Wi2 : Wp2) + ((g) & 7) * 32768; \
    st0 = *(const ushort8*)(p_ + (size_t)tid * 8); \
    st1 = *(const ushort8*)(p_ + (size_t)(1024 + tid) * 8); \
    st2 = *(const ushort8*)(p_ + (size_t)(2048 + tid) * 8); \
    st3 = *(const ushort8*)(p_ + (size_t)(3072 + tid) * 8); }

#define STW_ { \
    *(ushort8*)&w_lds[sr][sc]            = st0; \
    *(ushort8*)&w_lds[256 + sr][sc]      = st1; \
    *(ushort8*)&w_lds[sr][32 + sc]       = st2; \
    *(ushort8*)&w_lds[256 + sr][32 + sc] = st3; }

  LDW_(0);                                  // prologue stage

  // stage h to LDS
  *(ushort8*)&h_lds[tid >> 6][(tid & 63) * 8] = hv0;
  { int lin = 1024 + tid; *(ushort8*)&h_lds[lin >> 6][(lin & 63) * 8] = hv1; }

  f32x4 acc00 = {0.f,0.f,0.f,0.f}, acc01 = {0.f,0.f,0.f,0.f};
  f32x4 acc10 = {0.f,0.f,0.f,0.f}, acc11 = {0.f,0.f,0.f,0.f};

  const int o0 = wo + l15, o1 = wo + 16 + l15;

  for (int g = 0; g < 32; ++g) {            // 32 rounds x K=64 (4 steps x 8)
    __syncthreads();                         // w_lds free (prev round consumed)
    STW_;
    __syncthreads();                         // w_lds ready
    if (g + 1 < 32) LDW_(g + 1);            // issue next stage; waits at next STW_

    int kb = (g & 7) * 64 + quad * 8;       // h col base for kh=0
    #pragma unroll
    for (int kh = 0; kh < 2; ++kh) {
      bf16x8 a0 = *(const bf16x8*)&h_lds[l15][kb + kh * 32];
      bf16x8 a1 = *(const bf16x8*)&h_lds[16 + l15][kb + kh * 32];
      bf16x8 na = *(const bf16x8*)&w_lds[o0][kh * 32 + quad * 8];
      bf16x8 nb = *(const bf16x8*)&w_lds[o1][kh * 32 + quad * 8];
      acc00 = __builtin_amdgcn_mfma_f32_16x16x32_bf16(a0, na, acc00, 0, 0, 0);
      acc10 = __builtin_amdgcn_mfma_f32_16x16x32_bf16(a1, na, acc10, 0, 0, 0);
      acc01 = __builtin_amdgcn_mfma_f32_16x16x32_bf16(a0, nb, acc01, 0, 0, 0);
      acc11 = __builtin_amdgcn_mfma_f32_16x16x32_bf16(a1, nb, acc11, 0, 0, 0);
    }

    if ((g & 7) == 7 && g < 31) {           // end of INL step: in-LDS tanh update
      __syncthreads();
      #pragma unroll
      for (int r = 0; r < 4; ++r) {
        int sa = quad * 4 + r, sb = 16 + quad * 4 + r;
        h_lds[sa][o0] = f2bf_fast(bf2f(h_lds[sa][o0]) + DT_STEP * fast_tanh(acc00[r] + bi0));
        h_lds[sa][o1] = f2bf_fast(bf2f(h_lds[sa][o1]) + DT_STEP * fast_tanh(acc01[r] + bi1));
        h_lds[sb][o0] = f2bf_fast(bf2f(h_lds[sb][o0]) + DT_STEP * fast_tanh(acc10[r] + bi0));
        h_lds[sb][o1] = f2bf_fast(bf2f(h_lds[sb][o1]) + DT_STEP * fast_tanh(acc11[r] + bi1));
      }
      acc00 = (f32x4){0.f,0.f,0.f,0.f}; acc01 = (f32x4){0.f,0.f,0.f,0.f};
      acc10 = (f32x4){0.f,0.f,0.f,0.f}; acc11 = (f32x4){0.f,0.f,0.f,0.f};
      __syncthreads();
    }
  }

  // proj epilogue: Out[b][o][s0..] = x + pb + acc ; 4 consecutive s per reg quad -> f32x4
  {
    size_t base0 = (((size_t)b * 512 + o0) << 10) + (size_t)(s0 + quad * 4);
    size_t base1 = (((size_t)b * 512 + o1) << 10) + (size_t)(s0 + quad * 4);
    f32x4 xv, ov;
    xv = *(const f32x4*)(x + base0);
    #pragma unroll
    for (int r = 0; r < 4; ++r) ov[r] = xv[r] + bp0 + acc00[r];
    *(f32x4*)(Out + base0) = ov;
    xv = *(const f32x4*)(x + base0 + 16);
    #pragma unroll
    for (int r = 0; r < 4; ++r) ov[r] = xv[r] + bp0 + acc10[r];
    *(f32x4*)(Out + base0 + 16) = ov;
    xv = *(const f32x4*)(x + base1);
    #pragma unroll
    for (int r = 0; r < 4; ++r) ov[r] = xv[r] + bp1 + acc01[r];
    *(f32x4*)(Out + base1) = ov;
    xv = *(const f32x4*)(x + base1 + 16);
    #pragma unroll
    for (int r = 0; r < 4; ++r) ov[r] = xv[r] + bp1 + acc11[r];
    *(f32x4*)(Out + base1 + 16) = ov;
  }
#undef LDW_
#undef STW_
}

extern "C" void kernel_launch(void* const* d_in, const int* in_sizes, int n_in,
                              void* d_out, int out_size, void* d_ws, size_t ws_size,
                              hipStream_t stream) {
  const float* x        = (const float*)d_in[0];
  const float* gn_scale = (const float*)d_in[1];
  const float* gn_bias  = (const float*)d_in[2];
  const float* qkv_w    = (const float*)d_in[3];
  const float* qkv_b    = (const float*)d_in[4];
  const float* proj_w   = (const float*)d_in[5];
  const float* proj_b   = (const float*)d_in[6];
  const float* inl_w    = (const float*)d_in[7];
  const float* inl_b    = (const float*)d_in[8];
  float* out = (float*)d_out;
  float* ws = (float*)d_ws;

  unsigned short* Qt  = (unsigned short*)(ws + 8388608);
  unsigned short* Kt  = (unsigned short*)(ws + 10485760);
  unsigned short* Vt  = (unsigned short*)(ws + 12582912);
  unsigned short* h_t = (unsigned short*)(ws + 14680064);
  unsigned short* Abf = (unsigned short*)(ws + 16777216);
  float* gpart = ws + 18874368;
  unsigned short* qkvw_bf  = (unsigned short*)(ws + 18878464);
  unsigned short* inlw_bf  = qkvw_bf + 786432;
  unsigned short* projw_bf = inlw_bf + 262144;

  prep_kernel<<<1152, 256, 0, stream>>>(qkv_w, inl_w, proj_w, qkvw_bf, inlw_bf, projw_bf, x, gpart);
  gn_apply_t<<<1024, 256, 0, stream>>>(x, gpart, gn_scale, gn_bias, h_t);
  gemm_qkv_mfma<<<dim3(8, 12, 8), 256, 0, stream>>>(qkvw_bf, h_t, qkv_b, Qt, Kt, Vt);
  attn_mfma<<<512, 256, 0, stream>>>(Qt, Kt, Vt, Abf);
  inl_proj_chain<<<256, 1024, 0, stream>>>(Abf, inlw_bf, projw_bf, inl_b, proj_b, x, out);
}

// Round 11
// 184.552 us; speedup vs baseline: 1.0699x; 1.0699x over previous
//
#include <hip/hip_runtime.h>
#include <math.h>

#define B_ 8
#define C_ 512
#define S_ 1024
#define HD 64
#define NHEADS 8
#define NGROUPS 8
#define DT_STEP 0.1f
#define EPS_GN 1e-5f
#define LOG2E 1.4426950408889634f

typedef __attribute__((ext_vector_type(8))) short bf16x8;
typedef __attribute__((ext_vector_type(4))) float f32x4;
typedef __attribute__((ext_vector_type(8))) unsigned short ushort8;
typedef __attribute__((ext_vector_type(4))) unsigned short ushort4_t;

static __device__ __forceinline__ unsigned short f2bf(float f) {     // RNE (cold paths)
  unsigned int u = __builtin_bit_cast(unsigned int, f);
  u += 0x7fff + ((u >> 16) & 1);
  return (unsigned short)(u >> 16);
}

static __device__ __forceinline__ unsigned short f2bf_fast(float f) { // round-half-up (hot paths)
  unsigned int u = __builtin_bit_cast(unsigned int, f);
  return (unsigned short)((u + 0x8000u) >> 16);
}

static __device__ __forceinline__ float bf2f(unsigned short u) {
  unsigned int t = ((unsigned int)u) << 16;
  return __builtin_bit_cast(float, t);
}

static __device__ __forceinline__ float exp2_raw(float x) {
  return __builtin_amdgcn_exp2f(x);    // single v_exp_f32
}

static __device__ __forceinline__ float fast_tanh(float x) {
  float xc = fminf(fmaxf(x, -15.f), 15.f);
  float e = exp2_raw(xc * (2.0f * LOG2E));
  return (e - 1.f) / (e + 1.f);
}

// async global->LDS DMA, 16B per lane: LDS dest = wave-uniform base + lane*16,
// global src = per-lane. No destination registers -> nothing to sink or spill.
static __device__ __forceinline__ void gload_lds16(const unsigned short* g, unsigned short* l) {
  __builtin_amdgcn_global_load_lds(
      (const __attribute__((address_space(1))) unsigned int*)g,
      (__attribute__((address_space(3))) unsigned int*)l, 16, 0, 0);
}

// ---------------- prep: cast fp32 weights -> bf16  +  GroupNorm partial sums ----------------
// qkv_w: row-major [o][c] bf16 (consumed by gemm_nt_core LDS staging)
// inl_w / proj_w: SLAB-INTERLEAVED layout W2[(c>>5)*16384 + o*32 + (c&31)]
//   -> each 32-k slab is a contiguous 32KB block [512 o][32 k]; the chain kernel
//      DMA-stages one slab per round with fully-coalesced 16B/lane loads.
__global__ __launch_bounds__(256) void prep_kernel(
    const float* __restrict__ a, const float* __restrict__ b, const float* __restrict__ c,
    unsigned short* __restrict__ A, unsigned short* __restrict__ B, unsigned short* __restrict__ C,
    const float* __restrict__ x, float* __restrict__ gpart) {
  int bid = blockIdx.x;
  int tid = threadIdx.x;
  if (bid < 384) {                     // qkv weights: plain row-major cast
    int off = bid * 2048;
    int i = off + tid * 8;
    f32x4 v0 = *(const f32x4*)(a + i);
    f32x4 v1 = *(const f32x4*)(a + i + 4);
    ushort8 o;
    o[0] = f2bf(v0[0]); o[1] = f2bf(v0[1]); o[2] = f2bf(v0[2]); o[3] = f2bf(v0[3]);
    o[4] = f2bf(v1[0]); o[5] = f2bf(v1[1]); o[6] = f2bf(v1[2]); o[7] = f2bf(v1[3]);
    *(ushort8*)(A + i) = o;
    return;
  }
  if (bid < 640) {                     // inl/proj weights: slab-interleaved cast
    const float* src; unsigned short* dst; int off;
    if (bid < 512) { src = b; dst = B; off = (bid - 384) * 2048; }
    else { src = c; dst = C; off = (bid - 512) * 2048; }
    int i = off + tid * 8;
    f32x4 v0 = *(const f32x4*)(src + i);
    f32x4 v1 = *(const f32x4*)(src + i + 4);
    ushort8 o;
    o[0] = f2bf(v0[0]); o[1] = f2bf(v0[1]); o[2] = f2bf(v0[2]); o[3] = f2bf(v0[3]);
    o[4] = f2bf(v1[0]); o[5] = f2bf(v1[1]); o[6] = f2bf(v1[2]); o[7] = f2bf(v1[3]);
    int orow = i >> 9, cbase = i & 511;
    int dsti = (cbase >> 5) * 16384 + orow * 32 + (cbase & 31);
    *(ushort8*)(dst + dsti) = o;
    return;
  }
  int sbid = bid - 640;
  int bg = sbid >> 3, chunk = sbid & 7;
  const float* xp = x + (size_t)bg * 65536 + (size_t)chunk * 8192;
  float sum = 0.f, sq = 0.f;
  #pragma unroll
  for (int i = 0; i < 8; ++i) {
    f32x4 v = *(const f32x4*)(xp + i * 1024 + tid * 4);
    sum += v[0] + v[1] + v[2] + v[3];
    sq += v[0]*v[0] + v[1]*v[1] + v[2]*v[2] + v[3]*v[3];
  }
  #pragma unroll
  for (int off = 32; off >= 1; off >>= 1) {
    sum += __shfl_xor(sum, off, 64);
    sq  += __shfl_xor(sq, off, 64);
  }
  __shared__ float s1[4], s2[4];
  int wave = tid >> 6, lane = tid & 63;
  if (lane == 0) { s1[wave] = sum; s2[wave] = sq; }
  __syncthreads();
  if (tid == 0) {
    float S = s1[0] + s1[1] + s1[2] + s1[3];
    float Q = s2[0] + s2[1] + s2[2] + s2[3];
    gpart[bg * 16 + chunk * 2] = S;
    gpart[bg * 16 + chunk * 2 + 1] = Q;
  }
}

// ---------------- GroupNorm pass 2: normalize + transpose to h_t[B,S,C] bf16 ----------------
__global__ __launch_bounds__(256) void gn_apply_t(
    const float* __restrict__ x, const float* __restrict__ gpart,
    const float* __restrict__ scale, const float* __restrict__ bias,
    unsigned short* __restrict__ h_t) {
  int bid = blockIdx.x;
  int bg = bid >> 4, st = bid & 15;
  int b = bg >> 3, g = bg & 7;
  float S = 0.f, Q = 0.f;
  #pragma unroll
  for (int i = 0; i < 8; ++i) {
    S += gpart[bg * 16 + i * 2];
    Q += gpart[bg * 16 + i * 2 + 1];
  }
  float mean = S / 65536.f;
  float var = Q / 65536.f - mean * mean;
  float inv = rsqrtf(var + EPS_GN);

  int tid = threadIdx.x;
  int sl = tid >> 2;
  int cq = (tid & 3) * 16;
  float sA[16], sB[16];
  #pragma unroll
  for (int u = 0; u < 16; ++u) {
    float scv = scale[g * 64 + cq + u];
    sA[u] = inv * scv;
    sB[u] = bias[g * 64 + cq + u] - mean * inv * scv;
  }

  const float* xp = x + ((size_t)b * C_ + (size_t)g * 64) * S_;
  __shared__ float tile[64][65];
  #pragma unroll
  for (int it = 0; it < 16; ++it) {
    int lin = it * 256 + tid;
    int c = lin >> 6, s = lin & 63;
    tile[c][s] = xp[(size_t)c * S_ + st * 64 + s];
  }
  __syncthreads();
  unsigned short vals[16];
  #pragma unroll
  for (int u = 0; u < 16; ++u)
    vals[u] = f2bf_fast(tile[cq + u][sl] * sA[u] + sB[u]);
  unsigned short* dst = h_t + ((size_t)b * S_ + st * 64 + sl) * C_ + g * 64 + cq;
  ushort8 lo, hi;
  #pragma unroll
  for (int u = 0; u < 8; ++u) { lo[u] = vals[u]; hi[u] = vals[u + 8]; }
  *(ushort8*)dst = lo;
  *(ushort8*)(dst + 8) = hi;
}

// ---------------- NT GEMM core, register-prefetch pipelined staging ----------------
// C[MB,NB] = A[MB,512] * B[NB,512]^T ; next k-slab loads issue during MFMA phase.
template<int MB, int NB, int WMG, int WNG>
__device__ __forceinline__ void gemm_nt_core(
    const unsigned short* __restrict__ Ab,
    const unsigned short* __restrict__ Bb,
    unsigned short* ldsA, unsigned short* ldsB,
    f32x4* acc) {
  constexpr int TI = (MB / WMG) / 16;
  constexpr int TJ = (NB / WNG) / 16;
  constexpr int NQA = MB * 4 / 256;          // 16B chunks per thread (A)
  constexpr int NQB = NB * 4 / 256;
  const int K = 512;
  const int tid = threadIdx.x;
  const int w = tid >> 6, lane = tid & 63, quad = lane >> 4, l15 = lane & 15;
  const int wm = (WNG == 1) ? w : ((WMG == 1) ? 0 : (w >> 1));
  const int wn = (WNG == 1) ? 0 : ((WMG == 1) ? w : (w & 1));

  ushort8 apf[NQA], bpf[NQB];
  #pragma unroll
  for (int q = 0; q < NQA; ++q) {
    int c = q * 256 + tid;
    apf[q] = *(const ushort8*)(Ab + (size_t)(c >> 2) * K + (c & 3) * 8);
  }
  #pragma unroll
  for (int q = 0; q < NQB; ++q) {
    int c = q * 256 + tid;
    bpf[q] = *(const ushort8*)(Bb + (size_t)(c >> 2) * K + (c & 3) * 8);
  }

  for (int k0 = 0; k0 < K; k0 += 32) {
    __syncthreads();                         // prior slab consumed
    #pragma unroll
    for (int q = 0; q < NQA; ++q) {
      int c = q * 256 + tid;
      *(ushort8*)(ldsA + c * 8) = apf[q];
    }
    #pragma unroll
    for (int q = 0; q < NQB; ++q) {
      int c = q * 256 + tid;
      *(ushort8*)(ldsB + c * 8) = bpf[q];
    }
    __syncthreads();
    if (k0 + 32 < K) {                       // issue next-slab loads; waited next iter
      #pragma unroll
      for (int q = 0; q < NQA; ++q) {
        int c = q * 256 + tid;
        apf[q] = *(const ushort8*)(Ab + (size_t)(c >> 2) * K + k0 + 32 + (c & 3) * 8);
      }
      #pragma unroll
      for (int q = 0; q < NQB; ++q) {
        int c = q * 256 + tid;
        bpf[q] = *(const ushort8*)(Bb + (size_t)(c >> 2) * K + k0 + 32 + (c & 3) * 8);
      }
    }
    bf16x8 af[TI], bfr[TJ];
    #pragma unroll
    for (int i = 0; i < TI; ++i)
      af[i] = *(const bf16x8*)(ldsA + (wm * (MB / WMG) + i * 16 + l15) * 32 + quad * 8);
    #pragma unroll
    for (int j = 0; j < TJ; ++j)
      bfr[j] = *(const bf16x8*)(ldsB + (wn * (NB / WNG) + j * 16 + l15) * 32 + quad * 8);
    #pragma unroll
    for (int i = 0; i < TI; ++i)
      #pragma unroll
      for (int j = 0; j < TJ; ++j)
        acc[i * TJ + j] = __builtin_amdgcn_mfma_f32_16x16x32_bf16(af[i], bfr[j], acc[i * TJ + j], 0, 0, 0);
  }
}

// ---------------- QKV GEMM: W_bf[1536,512] x h_t[b][1024,512]^T ----------------
__global__ __launch_bounds__(256) void gemm_qkv_mfma(
    const unsigned short* __restrict__ Wbf, const unsigned short* __restrict__ h_t,
    const float* __restrict__ bias,
    unsigned short* __restrict__ Qt, unsigned short* __restrict__ Kt,
    unsigned short* __restrict__ Vt) {
  __shared__ __align__(16) unsigned short ldsA[128 * 32];
  __shared__ __align__(16) unsigned short ldsB[128 * 32];
  int b = blockIdx.z;
  int bm = blockIdx.y * 128, bn = blockIdx.x * 128;
  f32x4 acc[16];
  #pragma unroll
  for (int t = 0; t < 16; ++t) acc[t] = (f32x4){0.f, 0.f, 0.f, 0.f};
  gemm_nt_core<128, 128, 2, 2>(Wbf + (size_t)bm * 512,
                               h_t + ((size_t)b * S_ + bn) * 512, ldsA, ldsB, acc);
  int tid = threadIdx.x, w = tid >> 6, lane = tid & 63, quad = lane >> 4, l15 = lane & 15;
  int wm = w >> 1, wn = w & 1;
  int tensor = bm >> 9;
  float qscale = (tensor == 0) ? 0.125f * LOG2E : 1.0f;
  #pragma unroll
  for (int i = 0; i < 4; ++i) {
    #pragma unroll
    for (int j = 0; j < 4; ++j) {
      int m0 = bm + wm * 64 + i * 16 + quad * 4;
      int ng = bn + wn * 64 + j * 16 + l15;
      f32x4 v = acc[i * 4 + j];
      if (tensor < 2) {
        int head = (m0 >> 6) & 7, d0 = m0 & 63;
        ushort4_t pk;
        #pragma unroll
        for (int r = 0; r < 4; ++r) pk[r] = f2bf((v[r] + bias[m0 + r]) * qscale);
        unsigned short* dst = (tensor ? Kt : Qt) +
            (((size_t)(b * 8 + head) * S_ + ng) * 64 + d0);
        *(ushort4_t*)dst = pk;
      } else {
        #pragma unroll
        for (int r = 0; r < 4; ++r)
          Vt[(size_t)b * (C_ * S_) + (size_t)(m0 - 1024 + r) * S_ + ng] = f2bf(v[r] + bias[m0 + r]);
      }
    }
  }
}

// ---------------- Flash attention: transposed scores, 2 q-groups/wave, reg-prefetched K/V ----------------
// grid 512: bid = sblk*64 + (b*8+n); 4 waves x 32 q-rows (2 groups of 16)
__global__ __launch_bounds__(256) void attn_mfma(
    const unsigned short* __restrict__ Qt,   // [B][NH][S][HD] (pre-scaled, incl log2e)
    const unsigned short* __restrict__ Kt,
    const unsigned short* __restrict__ Vt,   // [B][C][S]
    unsigned short* __restrict__ hflat_bf) { // [B][S][C] bf16
  int tid = threadIdx.x, wave = tid >> 6, lane = tid & 63;
  int quad = lane >> 4, l15 = lane & 15;
  int bid = blockIdx.x;
  int bn = bid & 63, sblk = bid >> 6, b = bn >> 3, n = bn & 7;
  int s0w = sblk * 128 + wave * 32;

  __shared__ unsigned short k_lds[64][72];
  __shared__ unsigned short v_lds[64][72];
  __shared__ unsigned short p_lds[4][2][16][72];  // [wave][group][s][t], A-layout

  const unsigned short* Kb = Kt + ((size_t)(b * 8 + n)) * S_ * 64;
  const unsigned short* Vb = Vt + ((size_t)b * C_ + n * 64) * S_;

  bf16x8 qa[2][2];
  #pragma unroll
  for (int g = 0; g < 2; ++g) {
    const unsigned short* Qb = Qt + (((size_t)(b * 8 + n)) * S_ + s0w + g * 16 + l15) * 64;
    qa[g][0] = *(const bf16x8*)(Qb + quad * 8);
    qa[g][1] = *(const bf16x8*)(Qb + 32 + quad * 8);
  }

  bf16x8 ones;
  #pragma unroll
  for (int j = 0; j < 8; ++j) ones[j] = (short)0x3F80;

  f32x4 o_acc[2][4];
  f32x4 l_acc[2];
  #pragma unroll
  for (int g = 0; g < 2; ++g) {
    l_acc[g] = (f32x4){0.f, 0.f, 0.f, 0.f};
    #pragma unroll
    for (int dc = 0; dc < 4; ++dc) o_acc[g][dc] = (f32x4){0.f, 0.f, 0.f, 0.f};
  }

  int row0 = tid >> 3, c80 = (tid & 7) * 8;
  int row1 = (tid + 256) >> 3, c81 = c80;

  ushort8 kreg[2], vreg[2];
  kreg[0] = *(const ushort8*)(Kb + (size_t)row0 * 64 + c80);
  kreg[1] = *(const ushort8*)(Kb + (size_t)row1 * 64 + c81);
  vreg[0] = *(const ushort8*)(Vb + (size_t)row0 * S_ + c80);
  vreg[1] = *(const ushort8*)(Vb + (size_t)row1 * S_ + c81);

  for (int t0 = 0; t0 < S_; t0 += 64) {
    __syncthreads();
    *(ushort8*)&k_lds[row0][c80] = kreg[0];
    *(ushort8*)&k_lds[row1][c81] = kreg[1];
    *(ushort8*)&v_lds[row0][c80] = vreg[0];
    *(ushort8*)&v_lds[row1][c81] = vreg[1];
    __syncthreads();
    if (t0 + 64 < S_) {
      int t1 = t0 + 64;
      kreg[0] = *(const ushort8*)(Kb + (size_t)(t1 + row0) * 64 + c80);
      kreg[1] = *(const ushort8*)(Kb + (size_t)(t1 + row1) * 64 + c81);
      vreg[0] = *(const ushort8*)(Vb + (size_t)row0 * S_ + t1 + c80);
      vreg[1] = *(const ushort8*)(Vb + (size_t)row1 * S_ + t1 + c81);
    }

    // Transposed scores: St[t][s] = sum_d K[t][d] Q[s][d]
    f32x4 sc[2][4];
    #pragma unroll
    for (int tc = 0; tc < 4; ++tc) {
      bf16x8 kb0 = *(const bf16x8*)&k_lds[tc * 16 + l15][quad * 8];
      bf16x8 kb1 = *(const bf16x8*)&k_lds[tc * 16 + l15][32 + quad * 8];
      #pragma unroll
      for (int g = 0; g < 2; ++g) {
        f32x4 c = {0.f, 0.f, 0.f, 0.f};
        c = __builtin_amdgcn_mfma_f32_16x16x32_bf16(kb0, qa[g][0], c, 0, 0, 0);
        sc[g][tc] = __builtin_amdgcn_mfma_f32_16x16x32_bf16(kb1, qa[g][1], c, 0, 0, 0);
      }
    }

    // exp -> P[s][t] in LDS via contiguous b64 writes
    #pragma unroll
    for (int g = 0; g < 2; ++g)
      #pragma unroll
      for (int tc = 0; tc < 4; ++tc) {
        ushort4_t p4;
        #pragma unroll
        for (int r = 0; r < 4; ++r) p4[r] = f2bf_fast(exp2_raw(sc[g][tc][r]));
        *(ushort4_t*)&p_lds[wave][g][l15][tc * 16 + quad * 4] = p4;
      }

    bf16x8 pa[2][2];
    #pragma unroll
    for (int g = 0; g < 2; ++g) {
      pa[g][0] = *(const bf16x8*)&p_lds[wave][g][l15][quad * 8];
      pa[g][1] = *(const bf16x8*)&p_lds[wave][g][l15][32 + quad * 8];
      l_acc[g] = __builtin_amdgcn_mfma_f32_16x16x32_bf16(pa[g][0], ones, l_acc[g], 0, 0, 0);
      l_acc[g] = __builtin_amdgcn_mfma_f32_16x16x32_bf16(pa[g][1], ones, l_acc[g], 0, 0, 0);
    }
    #pragma unroll
    for (int dc = 0; dc < 4; ++dc) {
      bf16x8 vb0 = *(const bf16x8*)&v_lds[dc * 16 + l15][quad * 8];
      bf16x8 vb1 = *(const bf16x8*)&v_lds[dc * 16 + l15][32 + quad * 8];
      #pragma unroll
      for (int g = 0; g < 2; ++g) {
        o_acc[g][dc] = __builtin_amdgcn_mfma_f32_16x16x32_bf16(pa[g][0], vb0, o_acc[g][dc], 0, 0, 0);
        o_acc[g][dc] = __builtin_amdgcn_mfma_f32_16x16x32_bf16(pa[g][1], vb1, o_acc[g][dc], 0, 0, 0);
      }
    }
  }

  #pragma unroll
  for (int g = 0; g < 2; ++g) {
    float inv_l[4];
    #pragma unroll
    for (int r = 0; r < 4; ++r) inv_l[r] = 1.f / l_acc[g][r];
    #pragma unroll
    for (int dc = 0; dc < 4; ++dc) {
      #pragma unroll
      for (int r = 0; r < 4; ++r) {
        int s = s0w + g * 16 + quad * 4 + r;
        size_t idx = ((size_t)b * S_ + s) * C_ + n * 64 + dc * 16 + l15;
        hflat_bf[idx] = f2bf_fast(o_acc[g][dc][r] * inv_l[r]);
      }
    }
  }
}

// ---------------- Fused INL x3 + proj + residual: DMA-pipelined W stream ----------------
// 256 blocks x 1024 threads (16 waves). Block owns 32 h rows in LDS; W streams via
// global_load_lds into a double-buffered [512][32] slab image (32KB/slab, K=32/round).
// KEY INSIGHT vs rounds 3-10: (1) global_load_lds has NO destination registers ->
// nothing for the scheduler to sink (round-4 failure) and nothing for RA to spill
// (round-5/8 failures). (2) each wave consumes ONLY ITS OWN 32 W-rows, which it also
// loads itself -> per-wave counted vmcnt(2) suffices; NO barrier (and thus no vmcnt(0)
// drain) in the main loop. DMA for slab g+1 has a full round to land. Rounds are
// L2-BW-limited (~32KB/round/CU), not latency-limited.
__global__ __launch_bounds__(1024, 4) void inl_proj_chain(
    const unsigned short* __restrict__ hbf,   // [B*S][512] bf16 (attn out rows)
    const unsigned short* __restrict__ Wi2,   // inl W, slab-interleaved [16][512][32]
    const unsigned short* __restrict__ Wp2,   // proj W, slab-interleaved
    const float* __restrict__ ib, const float* __restrict__ pb,
    const float* __restrict__ x, float* __restrict__ Out) {
  __shared__ __align__(16) unsigned short h_lds[32][520];   // 33.3KB
  __shared__ __align__(16) unsigned short w_lds[2][16384];  // 64KB dbuf, [512 o][32 k]

  int tid = threadIdx.x;
  int wave = tid >> 6, lane = tid & 63, quad = lane >> 4, l15 = lane & 15;
  int wo = wave * 32;                        // this wave's 32 output channels = its W rows
  int bid = blockIdx.x;
  int b = bid >> 5, s0 = (bid & 31) * 32;    // 32 blocks per batch image

  const unsigned short* hsrc = hbf + (size_t)bid * 16384;
  ushort8 hv0 = *(const ushort8*)(hsrc + (size_t)tid * 8);
  ushort8 hv1 = *(const ushort8*)(hsrc + (size_t)(1024 + tid) * 8);

  float bi0 = ib[wo + l15], bi1 = ib[wo + 16 + l15];
  float bp0 = pb[wo + l15], bp1 = pb[wo + 16 + l15];

  *(ushort8*)&h_lds[tid >> 6][(tid & 63) * 8] = hv0;
  { int lin = 1024 + tid; *(ushort8*)&h_lds[lin >> 6][(lin & 63) * 8] = hv1; }

  f32x4 acc00 = {0.f,0.f,0.f,0.f}, acc01 = {0.f,0.f,0.f,0.f};
  f32x4 acc10 = {0.f,0.f,0.f,0.f}, acc11 = {0.f,0.f,0.f,0.f};

  const int o0 = wo + l15, o1 = wo + 16 + l15;
  const int wofs = wave * 1024;              // this wave's quarter... (1024 shorts = rows [wo,wo+32))
  const int lofs = lane * 8;                 // lane's 16B within a 512-short call

  __syncthreads();                           // h_lds ready (drains h loads; no DMA yet)

  // issue slab-g's 2 DMA calls into buf: wave loads exactly its own rows [wo, wo+32)
#define ISSUE_(g, buf) { \
    const unsigned short* ws_ = (((g) < 48) ? Wi2 : Wp2) + ((g) & 15) * 16384 + wofs; \
    gload_lds16(ws_ + lofs, &w_lds[buf][wofs]); \
    gload_lds16(ws_ + 512 + lofs, &w_lds[buf][wofs + 512]); }

  ISSUE_(0, 0);                              // prologue: slab 0 in flight

  for (int g = 0; g < 64; ++g) {
    int cur = g & 1;
    // own LDS reads of buf[cur^1] (round g-1) are complete before we overwrite it:
    asm volatile("s_waitcnt lgkmcnt(0)" ::: "memory");
    if (g + 1 < 64) {
      ISSUE_(g + 1, cur ^ 1);
      asm volatile("s_waitcnt vmcnt(2)" ::: "memory");   // slab g landed; g+1 stays in flight
    } else {
      asm volatile("s_waitcnt vmcnt(0)" ::: "memory");
    }

    int kb = (g & 15) * 32 + quad * 8;       // h col base for this slab's K-range
    bf16x8 a0 = *(const bf16x8*)&h_lds[l15][kb];
    bf16x8 a1 = *(const bf16x8*)&h_lds[16 + l15][kb];
    bf16x8 na = *(const bf16x8*)&w_lds[cur][o0 * 32 + quad * 8];
    bf16x8 nb = *(const bf16x8*)&w_lds[cur][o1 * 32 + quad * 8];
    acc00 = __builtin_amdgcn_mfma_f32_16x16x32_bf16(a0, na, acc00, 0, 0, 0);
    acc10 = __builtin_amdgcn_mfma_f32_16x16x32_bf16(a1, na, acc10, 0, 0, 0);
    acc01 = __builtin_amdgcn_mfma_f32_16x16x32_bf16(a0, nb, acc01, 0, 0, 0);
    acc11 = __builtin_amdgcn_mfma_f32_16x16x32_bf16(a1, nb, acc11, 0, 0, 0);

    if ((g & 15) == 15 && g < 63) {          // end of INL step: in-LDS tanh update
      __syncthreads();                       // drains vmcnt too; next round's vmcnt(2) passes free
      #pragma unroll
      for (int r = 0; r < 4; ++r) {
        int sa = quad * 4 + r, sb = 16 + quad * 4 + r;
        h_lds[sa][o0] = f2bf_fast(bf2f(h_lds[sa][o0]) + DT_STEP * fast_tanh(acc00[r] + bi0));
        h_lds[sa][o1] = f2bf_fast(bf2f(h_lds[sa][o1]) + DT_STEP * fast_tanh(acc01[r] + bi1));
        h_lds[sb][o0] = f2bf_fast(bf2f(h_lds[sb][o0]) + DT_STEP * fast_tanh(acc10[r] + bi0));
        h_lds[sb][o1] = f2bf_fast(bf2f(h_lds[sb][o1]) + DT_STEP * fast_tanh(acc11[r] + bi1));
      }
      acc00 = (f32x4){0.f,0.f,0.f,0.f}; acc01 = (f32x4){0.f,0.f,0.f,0.f};
      acc10 = (f32x4){0.f,0.f,0.f,0.f}; acc11 = (f32x4){0.f,0.f,0.f,0.f};
      __syncthreads();
    }
  }

  // proj epilogue: Out[b][o][s0..] = x + pb + acc ; 4 consecutive s per reg quad -> f32x4
  {
    size_t base0 = (((size_t)b * 512 + o0) << 10) + (size_t)(s0 + quad * 4);
    size_t base1 = (((size_t)b * 512 + o1) << 10) + (size_t)(s0 + quad * 4);
    f32x4 xv, ov;
    xv = *(const f32x4*)(x + base0);
    #pragma unroll
    for (int r = 0; r < 4; ++r) ov[r] = xv[r] + bp0 + acc00[r];
    *(f32x4*)(Out + base0) = ov;
    xv = *(const f32x4*)(x + base0 + 16);
    #pragma unroll
    for (int r = 0; r < 4; ++r) ov[r] = xv[r] + bp0 + acc10[r];
    *(f32x4*)(Out + base0 + 16) = ov;
    xv = *(const f32x4*)(x + base1);
    #pragma unroll
    for (int r = 0; r < 4; ++r) ov[r] = xv[r] + bp1 + acc01[r];
    *(f32x4*)(Out + base1) = ov;
    xv = *(const f32x4*)(x + base1 + 16);
    #pragma unroll
    for (int r = 0; r < 4; ++r) ov[r] = xv[r] + bp1 + acc11[r];
    *(f32x4*)(Out + base1 + 16) = ov;
  }
#undef ISSUE_
}

extern "C" void kernel_launch(void* const* d_in, const int* in_sizes, int n_in,
                              void* d_out, int out_size, void* d_ws, size_t ws_size,
                              hipStream_t stream) {
  const float* x        = (const float*)d_in[0];
  const float* gn_scale = (const float*)d_in[1];
  const float* gn_bias  = (const float*)d_in[2];
  const float* qkv_w    = (const float*)d_in[3];
  const float* qkv_b    = (const float*)d_in[4];
  const float* proj_w   = (const float*)d_in[5];
  const float* proj_b   = (const float*)d_in[6];
  const float* inl_w    = (const float*)d_in[7];
  const float* inl_b    = (const float*)d_in[8];
  float* out = (float*)d_out;
  float* ws = (float*)d_ws;

  unsigned short* Qt  = (unsigned short*)(ws + 8388608);
  unsigned short* Kt  = (unsigned short*)(ws + 10485760);
  unsigned short* Vt  = (unsigned short*)(ws + 12582912);
  unsigned short* h_t = (unsigned short*)(ws + 14680064);
  unsigned short* Abf = (unsigned short*)(ws + 16777216);
  float* gpart = ws + 18874368;
  unsigned short* qkvw_bf  = (unsigned short*)(ws + 18878464);
  unsigned short* inlw_bf  = qkvw_bf + 786432;
  unsigned short* projw_bf = inlw_bf + 262144;

  prep_kernel<<<1152, 256, 0, stream>>>(qkv_w, inl_w, proj_w, qkvw_bf, inlw_bf, projw_bf, x, gpart);
  gn_apply_t<<<1024, 256, 0, stream>>>(x, gpart, gn_scale, gn_bias, h_t);
  gemm_qkv_mfma<<<dim3(8, 12, 8), 256, 0, stream>>>(qkvw_bf, h_t, qkv_b, Qt, Kt, Vt);
  attn_mfma<<<512, 256, 0, stream>>>(Qt, Kt, Vt, Abf);
  inl_proj_chain<<<256, 1024, 0, stream>>>(Abf, inlw_bf, projw_bf, inl_b, proj_b, x, out);
}

// Round 12
// 183.112 us; speedup vs baseline: 1.0783x; 1.0079x over previous
//
#include <hip/hip_runtime.h>
#include <math.h>

#define B_ 8
#define C_ 512
#define S_ 1024
#define HD 64
#define NHEADS 8
#define NGROUPS 8
#define DT_STEP 0.1f
#define EPS_GN 1e-5f
#define LOG2E 1.4426950408889634f

typedef __attribute__((ext_vector_type(8))) short bf16x8;
typedef __attribute__((ext_vector_type(4))) float f32x4;
typedef __attribute__((ext_vector_type(8))) unsigned short ushort8;
typedef __attribute__((ext_vector_type(4))) unsigned short ushort4_t;

static __device__ __forceinline__ unsigned short f2bf(float f) {     // RNE (cold paths)
  unsigned int u = __builtin_bit_cast(unsigned int, f);
  u += 0x7fff + ((u >> 16) & 1);
  return (unsigned short)(u >> 16);
}

static __device__ __forceinline__ unsigned short f2bf_fast(float f) { // round-half-up (hot paths)
  unsigned int u = __builtin_bit_cast(unsigned int, f);
  return (unsigned short)((u + 0x8000u) >> 16);
}

static __device__ __forceinline__ float bf2f(unsigned short u) {
  unsigned int t = ((unsigned int)u) << 16;
  return __builtin_bit_cast(float, t);
}

static __device__ __forceinline__ float exp2_raw(float x) {
  return __builtin_amdgcn_exp2f(x);    // single v_exp_f32
}

static __device__ __forceinline__ float fast_tanh(float x) {
  float xc = fminf(fmaxf(x, -15.f), 15.f);
  float e = exp2_raw(xc * (2.0f * LOG2E));
  return (e - 1.f) / (e + 1.f);
}

// async global->LDS DMA, 16B per lane: LDS dest = wave-uniform base + lane*16,
// global src = per-lane. No destination registers -> nothing to sink or spill.
static __device__ __forceinline__ void gload_lds16(const unsigned short* g, unsigned short* l) {
  __builtin_amdgcn_global_load_lds(
      (const __attribute__((address_space(1))) unsigned int*)g,
      (__attribute__((address_space(3))) unsigned int*)l, 16, 0, 0);
}

// ---------------- prep: cast fp32 weights -> bf16  +  GroupNorm partial sums ----------------
// qkv_w: row-major [o][c] bf16 (consumed by gemm_nt_core LDS staging)
// inl_w / proj_w: SLAB-INTERLEAVED + CHUNK-SWIZZLED layout:
//   slab = c>>5 (32-k slabs of 32KB, [512 o][32 k]); within a row the four 8-short
//   chunks are XOR-permuted: chunk' = (kk>>3) ^ ((o>>1)&3).  The chain kernel's DMA
//   copies slabs linearly into LDS; its ds_read applies the same XOR -> W fragment
//   reads are bank-conflict-free (rule: swizzle global source + read, never DMA dest).
__global__ __launch_bounds__(256) void prep_kernel(
    const float* __restrict__ a, const float* __restrict__ b, const float* __restrict__ c,
    unsigned short* __restrict__ A, unsigned short* __restrict__ B, unsigned short* __restrict__ C,
    const float* __restrict__ x, float* __restrict__ gpart) {
  int bid = blockIdx.x;
  int tid = threadIdx.x;
  if (bid < 384) {                     // qkv weights: plain row-major cast
    int off = bid * 2048;
    int i = off + tid * 8;
    f32x4 v0 = *(const f32x4*)(a + i);
    f32x4 v1 = *(const f32x4*)(a + i + 4);
    ushort8 o;
    o[0] = f2bf(v0[0]); o[1] = f2bf(v0[1]); o[2] = f2bf(v0[2]); o[3] = f2bf(v0[3]);
    o[4] = f2bf(v1[0]); o[5] = f2bf(v1[1]); o[6] = f2bf(v1[2]); o[7] = f2bf(v1[3]);
    *(ushort8*)(A + i) = o;
    return;
  }
  if (bid < 640) {                     // inl/proj weights: slab-interleaved swizzled cast
    const float* src; unsigned short* dst; int off;
    if (bid < 512) { src = b; dst = B; off = (bid - 384) * 2048; }
    else { src = c; dst = C; off = (bid - 512) * 2048; }
    int i = off + tid * 8;
    f32x4 v0 = *(const f32x4*)(src + i);
    f32x4 v1 = *(const f32x4*)(src + i + 4);
    ushort8 o;
    o[0] = f2bf(v0[0]); o[1] = f2bf(v0[1]); o[2] = f2bf(v0[2]); o[3] = f2bf(v0[3]);
    o[4] = f2bf(v1[0]); o[5] = f2bf(v1[1]); o[6] = f2bf(v1[2]); o[7] = f2bf(v1[3]);
    int orow = i >> 9, cbase = i & 511;
    int chunk = ((cbase & 31) >> 3) ^ ((orow >> 1) & 3);
    int dsti = (cbase >> 5) * 16384 + orow * 32 + chunk * 8;
    *(ushort8*)(dst + dsti) = o;
    return;
  }
  int sbid = bid - 640;
  int bg = sbid >> 3, chunk = sbid & 7;
  const float* xp = x + (size_t)bg * 65536 + (size_t)chunk * 8192;
  float sum = 0.f, sq = 0.f;
  #pragma unroll
  for (int i = 0; i < 8; ++i) {
    f32x4 v = *(const f32x4*)(xp + i * 1024 + tid * 4);
    sum += v[0] + v[1] + v[2] + v[3];
    sq += v[0]*v[0] + v[1]*v[1] + v[2]*v[2] + v[3]*v[3];
  }
  #pragma unroll
  for (int off = 32; off >= 1; off >>= 1) {
    sum += __shfl_xor(sum, off, 64);
    sq  += __shfl_xor(sq, off, 64);
  }
  __shared__ float s1[4], s2[4];
  int wave = tid >> 6, lane = tid & 63;
  if (lane == 0) { s1[wave] = sum; s2[wave] = sq; }
  __syncthreads();
  if (tid == 0) {
    float S = s1[0] + s1[1] + s1[2] + s1[3];
    float Q = s2[0] + s2[1] + s2[2] + s2[3];
    gpart[bg * 16 + chunk * 2] = S;
    gpart[bg * 16 + chunk * 2 + 1] = Q;
  }
}

// ---------------- GroupNorm pass 2: normalize + transpose to h_t[B,S,C] bf16 ----------------
__global__ __launch_bounds__(256) void gn_apply_t(
    const float* __restrict__ x, const float* __restrict__ gpart,
    const float* __restrict__ scale, const float* __restrict__ bias,
    unsigned short* __restrict__ h_t) {
  int bid = blockIdx.x;
  int bg = bid >> 4, st = bid & 15;
  int b = bg >> 3, g = bg & 7;
  float S = 0.f, Q = 0.f;
  #pragma unroll
  for (int i = 0; i < 8; ++i) {
    S += gpart[bg * 16 + i * 2];
    Q += gpart[bg * 16 + i * 2 + 1];
  }
  float mean = S / 65536.f;
  float var = Q / 65536.f - mean * mean;
  float inv = rsqrtf(var + EPS_GN);

  int tid = threadIdx.x;
  int sl = tid >> 2;
  int cq = (tid & 3) * 16;
  float sA[16], sB[16];
  #pragma unroll
  for (int u = 0; u < 16; ++u) {
    float scv = scale[g * 64 + cq + u];
    sA[u] = inv * scv;
    sB[u] = bias[g * 64 + cq + u] - mean * inv * scv;
  }

  const float* xp = x + ((size_t)b * C_ + (size_t)g * 64) * S_;
  __shared__ float tile[64][65];
  #pragma unroll
  for (int it = 0; it < 16; ++it) {
    int lin = it * 256 + tid;
    int c = lin >> 6, s = lin & 63;
    tile[c][s] = xp[(size_t)c * S_ + st * 64 + s];
  }
  __syncthreads();
  unsigned short vals[16];
  #pragma unroll
  for (int u = 0; u < 16; ++u)
    vals[u] = f2bf_fast(tile[cq + u][sl] * sA[u] + sB[u]);
  unsigned short* dst = h_t + ((size_t)b * S_ + st * 64 + sl) * C_ + g * 64 + cq;
  ushort8 lo, hi;
  #pragma unroll
  for (int u = 0; u < 8; ++u) { lo[u] = vals[u]; hi[u] = vals[u + 8]; }
  *(ushort8*)dst = lo;
  *(ushort8*)(dst + 8) = hi;
}

// ---------------- NT GEMM core, register-prefetch pipelined staging ----------------
// C[MB,NB] = A[MB,512] * B[NB,512]^T ; next k-slab loads issue during MFMA phase.
template<int MB, int NB, int WMG, int WNG>
__device__ __forceinline__ void gemm_nt_core(
    const unsigned short* __restrict__ Ab,
    const unsigned short* __restrict__ Bb,
    unsigned short* ldsA, unsigned short* ldsB,
    f32x4* acc) {
  constexpr int TI = (MB / WMG) / 16;
  constexpr int TJ = (NB / WNG) / 16;
  constexpr int NQA = MB * 4 / 256;          // 16B chunks per thread (A)
  constexpr int NQB = NB * 4 / 256;
  const int K = 512;
  const int tid = threadIdx.x;
  const int w = tid >> 6, lane = tid & 63, quad = lane >> 4, l15 = lane & 15;
  const int wm = (WNG == 1) ? w : ((WMG == 1) ? 0 : (w >> 1));
  const int wn = (WNG == 1) ? 0 : ((WMG == 1) ? w : (w & 1));

  ushort8 apf[NQA], bpf[NQB];
  #pragma unroll
  for (int q = 0; q < NQA; ++q) {
    int c = q * 256 + tid;
    apf[q] = *(const ushort8*)(Ab + (size_t)(c >> 2) * K + (c & 3) * 8);
  }
  #pragma unroll
  for (int q = 0; q < NQB; ++q) {
    int c = q * 256 + tid;
    bpf[q] = *(const ushort8*)(Bb + (size_t)(c >> 2) * K + (c & 3) * 8);
  }

  for (int k0 = 0; k0 < K; k0 += 32) {
    __syncthreads();                         // prior slab consumed
    #pragma unroll
    for (int q = 0; q < NQA; ++q) {
      int c = q * 256 + tid;
      *(ushort8*)(ldsA + c * 8) = apf[q];
    }
    #pragma unroll
    for (int q = 0; q < NQB; ++q) {
      int c = q * 256 + tid;
      *(ushort8*)(ldsB + c * 8) = bpf[q];
    }
    __syncthreads();
    if (k0 + 32 < K) {                       // issue next-slab loads; waited next iter
      #pragma unroll
      for (int q = 0; q < NQA; ++q) {
        int c = q * 256 + tid;
        apf[q] = *(const ushort8*)(Ab + (size_t)(c >> 2) * K + k0 + 32 + (c & 3) * 8);
      }
      #pragma unroll
      for (int q = 0; q < NQB; ++q) {
        int c = q * 256 + tid;
        bpf[q] = *(const ushort8*)(Bb + (size_t)(c >> 2) * K + k0 + 32 + (c & 3) * 8);
      }
    }
    bf16x8 af[TI], bfr[TJ];
    #pragma unroll
    for (int i = 0; i < TI; ++i)
      af[i] = *(const bf16x8*)(ldsA + (wm * (MB / WMG) + i * 16 + l15) * 32 + quad * 8);
    #pragma unroll
    for (int j = 0; j < TJ; ++j)
      bfr[j] = *(const bf16x8*)(ldsB + (wn * (NB / WNG) + j * 16 + l15) * 32 + quad * 8);
    #pragma unroll
    for (int i = 0; i < TI; ++i)
      #pragma unroll
      for (int j = 0; j < TJ; ++j)
        acc[i * TJ + j] = __builtin_amdgcn_mfma_f32_16x16x32_bf16(af[i], bfr[j], acc[i * TJ + j], 0, 0, 0);
  }
}

// ---------------- QKV GEMM: W_bf[1536,512] x h_t[b][1024,512]^T ----------------
__global__ __launch_bounds__(256) void gemm_qkv_mfma(
    const unsigned short* __restrict__ Wbf, const unsigned short* __restrict__ h_t,
    const float* __restrict__ bias,
    unsigned short* __restrict__ Qt, unsigned short* __restrict__ Kt,
    unsigned short* __restrict__ Vt) {
  __shared__ __align__(16) unsigned short ldsA[128 * 32];
  __shared__ __align__(16) unsigned short ldsB[128 * 32];
  int b = blockIdx.z;
  int bm = blockIdx.y * 128, bn = blockIdx.x * 128;
  f32x4 acc[16];
  #pragma unroll
  for (int t = 0; t < 16; ++t) acc[t] = (f32x4){0.f, 0.f, 0.f, 0.f};
  gemm_nt_core<128, 128, 2, 2>(Wbf + (size_t)bm * 512,
                               h_t + ((size_t)b * S_ + bn) * 512, ldsA, ldsB, acc);
  int tid = threadIdx.x, w = tid >> 6, lane = tid & 63, quad = lane >> 4, l15 = lane & 15;
  int wm = w >> 1, wn = w & 1;
  int tensor = bm >> 9;
  float qscale = (tensor == 0) ? 0.125f * LOG2E : 1.0f;
  #pragma unroll
  for (int i = 0; i < 4; ++i) {
    #pragma unroll
    for (int j = 0; j < 4; ++j) {
      int m0 = bm + wm * 64 + i * 16 + quad * 4;
      int ng = bn + wn * 64 + j * 16 + l15;
      f32x4 v = acc[i * 4 + j];
      if (tensor < 2) {
        int head = (m0 >> 6) & 7, d0 = m0 & 63;
        ushort4_t pk;
        #pragma unroll
        for (int r = 0; r < 4; ++r) pk[r] = f2bf((v[r] + bias[m0 + r]) * qscale);
        unsigned short* dst = (tensor ? Kt : Qt) +
            (((size_t)(b * 8 + head) * S_ + ng) * 64 + d0);
        *(ushort4_t*)dst = pk;
      } else {
        #pragma unroll
        for (int r = 0; r < 4; ++r)
          Vt[(size_t)b * (C_ * S_) + (size_t)(m0 - 1024 + r) * S_ + ng] = f2bf(v[r] + bias[m0 + r]);
      }
    }
  }
}

// ---------------- Flash attention: transposed scores, 2 q-groups/wave, reg-prefetched K/V ----------------
// grid 512: bid = sblk*64 + (b*8+n); 4 waves x 32 q-rows (2 groups of 16)
__global__ __launch_bounds__(256) void attn_mfma(
    const unsigned short* __restrict__ Qt,   // [B][NH][S][HD] (pre-scaled, incl log2e)
    const unsigned short* __restrict__ Kt,
    const unsigned short* __restrict__ Vt,   // [B][C][S]
    unsigned short* __restrict__ hflat_bf) { // [B][S][C] bf16
  int tid = threadIdx.x, wave = tid >> 6, lane = tid & 63;
  int quad = lane >> 4, l15 = lane & 15;
  int bid = blockIdx.x;
  int bn = bid & 63, sblk = bid >> 6, b = bn >> 3, n = bn & 7;
  int s0w = sblk * 128 + wave * 32;

  __shared__ unsigned short k_lds[64][72];
  __shared__ unsigned short v_lds[64][72];
  __shared__ unsigned short p_lds[4][2][16][72];  // [wave][group][s][t], A-layout

  const unsigned short* Kb = Kt + ((size_t)(b * 8 + n)) * S_ * 64;
  const unsigned short* Vb = Vt + ((size_t)b * C_ + n * 64) * S_;

  bf16x8 qa[2][2];
  #pragma unroll
  for (int g = 0; g < 2; ++g) {
    const unsigned short* Qb = Qt + (((size_t)(b * 8 + n)) * S_ + s0w + g * 16 + l15) * 64;
    qa[g][0] = *(const bf16x8*)(Qb + quad * 8);
    qa[g][1] = *(const bf16x8*)(Qb + 32 + quad * 8);
  }

  bf16x8 ones;
  #pragma unroll
  for (int j = 0; j < 8; ++j) ones[j] = (short)0x3F80;

  f32x4 o_acc[2][4];
  f32x4 l_acc[2];
  #pragma unroll
  for (int g = 0; g < 2; ++g) {
    l_acc[g] = (f32x4){0.f, 0.f, 0.f, 0.f};
    #pragma unroll
    for (int dc = 0; dc < 4; ++dc) o_acc[g][dc] = (f32x4){0.f, 0.f, 0.f, 0.f};
  }

  int row0 = tid >> 3, c80 = (tid & 7) * 8;
  int row1 = (tid + 256) >> 3, c81 = c80;

  ushort8 kreg[2], vreg[2];
  kreg[0] = *(const ushort8*)(Kb + (size_t)row0 * 64 + c80);
  kreg[1] = *(const ushort8*)(Kb + (size_t)row1 * 64 + c81);
  vreg[0] = *(const ushort8*)(Vb + (size_t)row0 * S_ + c80);
  vreg[1] = *(const ushort8*)(Vb + (size_t)row1 * S_ + c81);

  for (int t0 = 0; t0 < S_; t0 += 64) {
    __syncthreads();
    *(ushort8*)&k_lds[row0][c80] = kreg[0];
    *(ushort8*)&k_lds[row1][c81] = kreg[1];
    *(ushort8*)&v_lds[row0][c80] = vreg[0];
    *(ushort8*)&v_lds[row1][c81] = vreg[1];
    __syncthreads();
    if (t0 + 64 < S_) {
      int t1 = t0 + 64;
      kreg[0] = *(const ushort8*)(Kb + (size_t)(t1 + row0) * 64 + c80);
      kreg[1] = *(const ushort8*)(Kb + (size_t)(t1 + row1) * 64 + c81);
      vreg[0] = *(const ushort8*)(Vb + (size_t)row0 * S_ + t1 + c80);
      vreg[1] = *(const ushort8*)(Vb + (size_t)row1 * S_ + t1 + c81);
    }

    // Transposed scores: St[t][s] = sum_d K[t][d] Q[s][d]
    f32x4 sc[2][4];
    #pragma unroll
    for (int tc = 0; tc < 4; ++tc) {
      bf16x8 kb0 = *(const bf16x8*)&k_lds[tc * 16 + l15][quad * 8];
      bf16x8 kb1 = *(const bf16x8*)&k_lds[tc * 16 + l15][32 + quad * 8];
      #pragma unroll
      for (int g = 0; g < 2; ++g) {
        f32x4 c = {0.f, 0.f, 0.f, 0.f};
        c = __builtin_amdgcn_mfma_f32_16x16x32_bf16(kb0, qa[g][0], c, 0, 0, 0);
        sc[g][tc] = __builtin_amdgcn_mfma_f32_16x16x32_bf16(kb1, qa[g][1], c, 0, 0, 0);
      }
    }

    // exp -> P[s][t] in LDS via contiguous b64 writes
    #pragma unroll
    for (int g = 0; g < 2; ++g)
      #pragma unroll
      for (int tc = 0; tc < 4; ++tc) {
        ushort4_t p4;
        #pragma unroll
        for (int r = 0; r < 4; ++r) p4[r] = f2bf_fast(exp2_raw(sc[g][tc][r]));
        *(ushort4_t*)&p_lds[wave][g][l15][tc * 16 + quad * 4] = p4;
      }

    bf16x8 pa[2][2];
    #pragma unroll
    for (int g = 0; g < 2; ++g) {
      pa[g][0] = *(const bf16x8*)&p_lds[wave][g][l15][quad * 8];
      pa[g][1] = *(const bf16x8*)&p_lds[wave][g][l15][32 + quad * 8];
      l_acc[g] = __builtin_amdgcn_mfma_f32_16x16x32_bf16(pa[g][0], ones, l_acc[g], 0, 0, 0);
      l_acc[g] = __builtin_amdgcn_mfma_f32_16x16x32_bf16(pa[g][1], ones, l_acc[g], 0, 0, 0);
    }
    #pragma unroll
    for (int dc = 0; dc < 4; ++dc) {
      bf16x8 vb0 = *(const bf16x8*)&v_lds[dc * 16 + l15][quad * 8];
      bf16x8 vb1 = *(const bf16x8*)&v_lds[dc * 16 + l15][32 + quad * 8];
      #pragma unroll
      for (int g = 0; g < 2; ++g) {
        o_acc[g][dc] = __builtin_amdgcn_mfma_f32_16x16x32_bf16(pa[g][0], vb0, o_acc[g][dc], 0, 0, 0);
        o_acc[g][dc] = __builtin_amdgcn_mfma_f32_16x16x32_bf16(pa[g][1], vb1, o_acc[g][dc], 0, 0, 0);
      }
    }
  }

  #pragma unroll
  for (int g = 0; g < 2; ++g) {
    float inv_l[4];
    #pragma unroll
    for (int r = 0; r < 4; ++r) inv_l[r] = 1.f / l_acc[g][r];
    #pragma unroll
    for (int dc = 0; dc < 4; ++dc) {
      #pragma unroll
      for (int r = 0; r < 4; ++r) {
        int s = s0w + g * 16 + quad * 4 + r;
        size_t idx = ((size_t)b * S_ + s) * C_ + n * 64 + dc * 16 + l15;
        hflat_bf[idx] = f2bf_fast(o_acc[g][dc][r] * inv_l[r]);
      }
    }
  }
}

// ---------------- Fused INL x3 + proj + residual: DMA-pipelined, LDS-BW-optimized ----------------
// Round-11 diagnosis: dur invariant (44us) across latency mechanisms => LDS-BW-bound:
// 16 waves x 4 b128/round = 64KB read + 32KB DMA write per round, W-frag reads 8-way
// bank-conflicted (64B row stride), h reads duplicated 16x across waves.
// This version: 8 waves x 64 o-cols (TJ=4) -> 48KB read/round (h dup halved, 0.75
// reads/MFMA); W chunk-XOR swizzle (global-source side) -> conflict-free W reads;
// 64 rounds fully unrolled (compile-time slab offsets). DMA skeleton unchanged:
// per-wave self-loading, counted vmcnt(4), no main-loop barrier.
__global__ __launch_bounds__(512, 2) void inl_proj_chain(
    const unsigned short* __restrict__ hbf,   // [B*S][512] bf16 (attn out rows)
    const unsigned short* __restrict__ Wi2,   // inl W, swizzled slab-interleaved
    const unsigned short* __restrict__ Wp2,   // proj W, swizzled slab-interleaved
    const float* __restrict__ ib, const float* __restrict__ pb,
    const float* __restrict__ x, float* __restrict__ Out) {
  __shared__ __align__(16) unsigned short h_lds[32][520];   // 33.3KB
  __shared__ __align__(16) unsigned short w_lds[2][16384];  // 64KB dbuf, [512 o][32 k]

  int tid = threadIdx.x;
  int wave = tid >> 6, lane = tid & 63, quad = lane >> 4, l15 = lane & 15;
  int wo = wave * 64;                        // this wave's 64 output channels = its W rows
  int bid = blockIdx.x;
  int b = bid >> 5, s0 = (bid & 31) * 32;    // 32 blocks per batch image

  const unsigned short* hsrc = hbf + (size_t)bid * 16384;
  ushort8 hv0 = *(const ushort8*)(hsrc + (size_t)tid * 8);
  ushort8 hv1 = *(const ushort8*)(hsrc + (size_t)(512 + tid) * 8);
  ushort8 hv2 = *(const ushort8*)(hsrc + (size_t)(1024 + tid) * 8);
  ushort8 hv3 = *(const ushort8*)(hsrc + (size_t)(1536 + tid) * 8);

  float bi0 = ib[wo + l15],      bi1 = ib[wo + 16 + l15];
  float bi2 = ib[wo + 32 + l15], bi3 = ib[wo + 48 + l15];
  float bp0 = pb[wo + l15],      bp1 = pb[wo + 16 + l15];
  float bp2 = pb[wo + 32 + l15], bp3 = pb[wo + 48 + l15];

  *(ushort8*)&h_lds[tid >> 6][(tid & 63) * 8] = hv0;
  { int lin = 512 + tid;  *(ushort8*)&h_lds[lin >> 6][(lin & 63) * 8] = hv1; }
  { int lin = 1024 + tid; *(ushort8*)&h_lds[lin >> 6][(lin & 63) * 8] = hv2; }
  { int lin = 1536 + tid; *(ushort8*)&h_lds[lin >> 6][(lin & 63) * 8] = hv3; }

  f32x4 acc00 = {0.f,0.f,0.f,0.f}, acc01 = {0.f,0.f,0.f,0.f};
  f32x4 acc02 = {0.f,0.f,0.f,0.f}, acc03 = {0.f,0.f,0.f,0.f};
  f32x4 acc10 = {0.f,0.f,0.f,0.f}, acc11 = {0.f,0.f,0.f,0.f};
  f32x4 acc12 = {0.f,0.f,0.f,0.f}, acc13 = {0.f,0.f,0.f,0.f};

  const int o0 = wo + l15,      o1 = wo + 16 + l15;
  const int o2 = wo + 32 + l15, o3 = wo + 48 + l15;
  const int wofs = wave * 2048;              // 64 rows x 32 shorts
  const int lofs = lane * 8;                 // lane's 16B within a 1KB DMA call
  const int wcol = (quad ^ ((l15 >> 1) & 3)) * 8;   // chunk-XOR read swizzle (matches prep)

  __syncthreads();                           // h_lds ready (drains h loads; no DMA yet)

#define ISSUE_(base, slab, buf) { \
    const unsigned short* ws_ = (base) + (slab) * 16384 + wofs; \
    gload_lds16(ws_ + lofs, &w_lds[buf][wofs]); \
    gload_lds16(ws_ + 512 + lofs, &w_lds[buf][wofs + 512]); \
    gload_lds16(ws_ + 1024 + lofs, &w_lds[buf][wofs + 1024]); \
    gload_lds16(ws_ + 1536 + lofs, &w_lds[buf][wofs + 1536]); }

  ISSUE_(Wi2, 0, 0);                         // prologue: slab 0 in flight

  #pragma unroll
  for (int step = 0; step < 4; ++step) {
    #pragma unroll
    for (int s = 0; s < 16; ++s) {
      const int g = step * 16 + s;
      const int cur = g & 1;
      asm volatile("s_waitcnt lgkmcnt(0)" ::: "memory");  // own prev-round reads done
      if (g + 1 < 64) {
        const unsigned short* nb_ = ((g + 1) < 48) ? Wi2 : Wp2;
        ISSUE_(nb_, (g + 1) & 15, cur ^ 1);
        asm volatile("s_waitcnt vmcnt(4)" ::: "memory");  // slab g landed; g+1 in flight
      } else {
        asm volatile("s_waitcnt vmcnt(0)" ::: "memory");
      }

      const int kb = s * 32 + quad * 8;
      bf16x8 a0 = *(const bf16x8*)&h_lds[l15][kb];
      bf16x8 a1 = *(const bf16x8*)&h_lds[16 + l15][kb];
      bf16x8 w0 = *(const bf16x8*)&w_lds[cur][o0 * 32 + wcol];
      bf16x8 w1 = *(const bf16x8*)&w_lds[cur][o1 * 32 + wcol];
      bf16x8 w2 = *(const bf16x8*)&w_lds[cur][o2 * 32 + wcol];
      bf16x8 w3 = *(const bf16x8*)&w_lds[cur][o3 * 32 + wcol];
      acc00 = __builtin_amdgcn_mfma_f32_16x16x32_bf16(a0, w0, acc00, 0, 0, 0);
      acc10 = __builtin_amdgcn_mfma_f32_16x16x32_bf16(a1, w0, acc10, 0, 0, 0);
      acc01 = __builtin_amdgcn_mfma_f32_16x16x32_bf16(a0, w1, acc01, 0, 0, 0);
      acc11 = __builtin_amdgcn_mfma_f32_16x16x32_bf16(a1, w1, acc11, 0, 0, 0);
      acc02 = __builtin_amdgcn_mfma_f32_16x16x32_bf16(a0, w2, acc02, 0, 0, 0);
      acc12 = __builtin_amdgcn_mfma_f32_16x16x32_bf16(a1, w2, acc12, 0, 0, 0);
      acc03 = __builtin_amdgcn_mfma_f32_16x16x32_bf16(a0, w3, acc03, 0, 0, 0);
      acc13 = __builtin_amdgcn_mfma_f32_16x16x32_bf16(a1, w3, acc13, 0, 0, 0);
    }

    if (step < 3) {                          // end of INL step: in-LDS tanh update
      __syncthreads();
      #pragma unroll
      for (int r = 0; r < 4; ++r) {
        int sa = quad * 4 + r, sb = 16 + quad * 4 + r;
        h_lds[sa][o0] = f2bf_fast(bf2f(h_lds[sa][o0]) + DT_STEP * fast_tanh(acc00[r] + bi0));
        h_lds[sa][o1] = f2bf_fast(bf2f(h_lds[sa][o1]) + DT_STEP * fast_tanh(acc01[r] + bi1));
        h_lds[sa][o2] = f2bf_fast(bf2f(h_lds[sa][o2]) + DT_STEP * fast_tanh(acc02[r] + bi2));
        h_lds[sa][o3] = f2bf_fast(bf2f(h_lds[sa][o3]) + DT_STEP * fast_tanh(acc03[r] + bi3));
        h_lds[sb][o0] = f2bf_fast(bf2f(h_lds[sb][o0]) + DT_STEP * fast_tanh(acc10[r] + bi0));
        h_lds[sb][o1] = f2bf_fast(bf2f(h_lds[sb][o1]) + DT_STEP * fast_tanh(acc11[r] + bi1));
        h_lds[sb][o2] = f2bf_fast(bf2f(h_lds[sb][o2]) + DT_STEP * fast_tanh(acc12[r] + bi2));
        h_lds[sb][o3] = f2bf_fast(bf2f(h_lds[sb][o3]) + DT_STEP * fast_tanh(acc13[r] + bi3));
      }
      acc00 = (f32x4){0.f,0.f,0.f,0.f}; acc01 = (f32x4){0.f,0.f,0.f,0.f};
      acc02 = (f32x4){0.f,0.f,0.f,0.f}; acc03 = (f32x4){0.f,0.f,0.f,0.f};
      acc10 = (f32x4){0.f,0.f,0.f,0.f}; acc11 = (f32x4){0.f,0.f,0.f,0.f};
      acc12 = (f32x4){0.f,0.f,0.f,0.f}; acc13 = (f32x4){0.f,0.f,0.f,0.f};
      __syncthreads();
    }
  }

  // proj epilogue: Out[b][o][s0..] = x + pb + acc ; 4 consecutive s per reg quad -> f32x4
#define EPI_(oj, bpj, aI0, aI1) { \
    size_t base_ = (((size_t)b * 512 + (oj)) << 10) + (size_t)(s0 + quad * 4); \
    f32x4 xv_, ov_; \
    xv_ = *(const f32x4*)(x + base_); \
    _Pragma("unroll") \
    for (int r = 0; r < 4; ++r) ov_[r] = xv_[r] + (bpj) + aI0[r]; \
    *(f32x4*)(Out + base_) = ov_; \
    xv_ = *(const f32x4*)(x + base_ + 16); \
    _Pragma("unroll") \
    for (int r = 0; r < 4; ++r) ov_[r] = xv_[r] + (bpj) + aI1[r]; \
    *(f32x4*)(Out + base_ + 16) = ov_; }

  EPI_(o0, bp0, acc00, acc10);
  EPI_(o1, bp1, acc01, acc11);
  EPI_(o2, bp2, acc02, acc12);
  EPI_(o3, bp3, acc03, acc13);
#undef EPI_
#undef ISSUE_
}

extern "C" void kernel_launch(void* const* d_in, const int* in_sizes, int n_in,
                              void* d_out, int out_size, void* d_ws, size_t ws_size,
                              hipStream_t stream) {
  const float* x        = (const float*)d_in[0];
  const float* gn_scale = (const float*)d_in[1];
  const float* gn_bias  = (const float*)d_in[2];
  const float* qkv_w    = (const float*)d_in[3];
  const float* qkv_b    = (const float*)d_in[4];
  const float* proj_w   = (const float*)d_in[5];
  const float* proj_b   = (const float*)d_in[6];
  const float* inl_w    = (const float*)d_in[7];
  const float* inl_b    = (const float*)d_in[8];
  float* out = (float*)d_out;
  float* ws = (float*)d_ws;

  unsigned short* Qt  = (unsigned short*)(ws + 8388608);
  unsigned short* Kt  = (unsigned short*)(ws + 10485760);
  unsigned short* Vt  = (unsigned short*)(ws + 12582912);
  unsigned short* h_t = (unsigned short*)(ws + 14680064);
  unsigned short* Abf = (unsigned short*)(ws + 16777216);
  float* gpart = ws + 18874368;
  unsigned short* qkvw_bf  = (unsigned short*)(ws + 18878464);
  unsigned short* inlw_bf  = qkvw_bf + 786432;
  unsigned short* projw_bf = inlw_bf + 262144;

  prep_kernel<<<1152, 256, 0, stream>>>(qkv_w, inl_w, proj_w, qkvw_bf, inlw_bf, projw_bf, x, gpart);
  gn_apply_t<<<1024, 256, 0, stream>>>(x, gpart, gn_scale, gn_bias, h_t);
  gemm_qkv_mfma<<<dim3(8, 12, 8), 256, 0, stream>>>(qkvw_bf, h_t, qkv_b, Qt, Kt, Vt);
  attn_mfma<<<512, 256, 0, stream>>>(Qt, Kt, Vt, Abf);
  inl_proj_chain<<<256, 512, 0, stream>>>(Abf, inlw_bf, projw_bf, inl_b, proj_b, x, out);
}

// Round 13
// 180.213 us; speedup vs baseline: 1.0956x; 1.0161x over previous
//
#include <hip/hip_runtime.h>
#include <math.h>

#define B_ 8
#define C_ 512
#define S_ 1024
#define HD 64
#define NHEADS 8
#define NGROUPS 8
#define DT_STEP 0.1f
#define EPS_GN 1e-5f
#define LOG2E 1.4426950408889634f

typedef __attribute__((ext_vector_type(8))) short bf16x8;
typedef __attribute__((ext_vector_type(4))) float f32x4;
typedef __attribute__((ext_vector_type(8))) unsigned short ushort8;
typedef __attribute__((ext_vector_type(4))) unsigned short ushort4_t;

static __device__ __forceinline__ unsigned short f2bf(float f) {     // RNE (cold paths)
  unsigned int u = __builtin_bit_cast(unsigned int, f);
  u += 0x7fff + ((u >> 16) & 1);
  return (unsigned short)(u >> 16);
}

static __device__ __forceinline__ unsigned short f2bf_fast(float f) { // round-half-up (hot paths)
  unsigned int u = __builtin_bit_cast(unsigned int, f);
  return (unsigned short)((u + 0x8000u) >> 16);
}

static __device__ __forceinline__ float bf2f(unsigned short u) {
  unsigned int t = ((unsigned int)u) << 16;
  return __builtin_bit_cast(float, t);
}

static __device__ __forceinline__ float exp2_raw(float x) {
  return __builtin_amdgcn_exp2f(x);    // single v_exp_f32
}

static __device__ __forceinline__ float fast_tanh(float x) {
  float xc = fminf(fmaxf(x, -15.f), 15.f);
  float e = exp2_raw(xc * (2.0f * LOG2E));
  return (e - 1.f) / (e + 1.f);
}

// async global->LDS DMA, 16B per lane: LDS dest = wave-uniform base + lane*16,
// global src = per-lane. No destination registers -> nothing to sink or spill.
static __device__ __forceinline__ void gload_lds16(const unsigned short* g, unsigned short* l) {
  __builtin_amdgcn_global_load_lds(
      (const __attribute__((address_space(1))) unsigned int*)g,
      (__attribute__((address_space(3))) unsigned int*)l, 16, 0, 0);
}

// ---------------- prep: cast fp32 weights -> bf16  +  GroupNorm partial sums ----------------
// qkv_w: row-major [o][c] bf16 (consumed by gemm_nt_core LDS staging)
// inl_w / proj_w: SLAB-INTERLEAVED + CHUNK-SWIZZLED layout:
//   slab = c>>5 (32-k slabs of 32KB, [512 o][32 k]); within a row the four 8-short
//   chunks are XOR-permuted: chunk' = (kk>>3) ^ ((o>>1)&3).  The chain kernel's DMA
//   copies slabs linearly into LDS; its ds_read applies the same XOR -> W fragment
//   reads are bank-conflict-free (rule: swizzle global source + read, never DMA dest).
__global__ __launch_bounds__(256) void prep_kernel(
    const float* __restrict__ a, const float* __restrict__ b, const float* __restrict__ c,
    unsigned short* __restrict__ A, unsigned short* __restrict__ B, unsigned short* __restrict__ C,
    const float* __restrict__ x, float* __restrict__ gpart) {
  int bid = blockIdx.x;
  int tid = threadIdx.x;
  if (bid < 384) {                     // qkv weights: plain row-major cast
    int off = bid * 2048;
    int i = off + tid * 8;
    f32x4 v0 = *(const f32x4*)(a + i);
    f32x4 v1 = *(const f32x4*)(a + i + 4);
    ushort8 o;
    o[0] = f2bf(v0[0]); o[1] = f2bf(v0[1]); o[2] = f2bf(v0[2]); o[3] = f2bf(v0[3]);
    o[4] = f2bf(v1[0]); o[5] = f2bf(v1[1]); o[6] = f2bf(v1[2]); o[7] = f2bf(v1[3]);
    *(ushort8*)(A + i) = o;
    return;
  }
  if (bid < 640) {                     // inl/proj weights: slab-interleaved swizzled cast
    const float* src; unsigned short* dst; int off;
    if (bid < 512) { src = b; dst = B; off = (bid - 384) * 2048; }
    else { src = c; dst = C; off = (bid - 512) * 2048; }
    int i = off + tid * 8;
    f32x4 v0 = *(const f32x4*)(src + i);
    f32x4 v1 = *(const f32x4*)(src + i + 4);
    ushort8 o;
    o[0] = f2bf(v0[0]); o[1] = f2bf(v0[1]); o[2] = f2bf(v0[2]); o[3] = f2bf(v0[3]);
    o[4] = f2bf(v1[0]); o[5] = f2bf(v1[1]); o[6] = f2bf(v1[2]); o[7] = f2bf(v1[3]);
    int orow = i >> 9, cbase = i & 511;
    int chunk = ((cbase & 31) >> 3) ^ ((orow >> 1) & 3);
    int dsti = (cbase >> 5) * 16384 + orow * 32 + chunk * 8;
    *(ushort8*)(dst + dsti) = o;
    return;
  }
  int sbid = bid - 640;
  int bg = sbid >> 3, chunk = sbid & 7;
  const float* xp = x + (size_t)bg * 65536 + (size_t)chunk * 8192;
  float sum = 0.f, sq = 0.f;
  #pragma unroll
  for (int i = 0; i < 8; ++i) {
    f32x4 v = *(const f32x4*)(xp + i * 1024 + tid * 4);
    sum += v[0] + v[1] + v[2] + v[3];
    sq += v[0]*v[0] + v[1]*v[1] + v[2]*v[2] + v[3]*v[3];
  }
  #pragma unroll
  for (int off = 32; off >= 1; off >>= 1) {
    sum += __shfl_xor(sum, off, 64);
    sq  += __shfl_xor(sq, off, 64);
  }
  __shared__ float s1[4], s2[4];
  int wave = tid >> 6, lane = tid & 63;
  if (lane == 0) { s1[wave] = sum; s2[wave] = sq; }
  __syncthreads();
  if (tid == 0) {
    float S = s1[0] + s1[1] + s1[2] + s1[3];
    float Q = s2[0] + s2[1] + s2[2] + s2[3];
    gpart[bg * 16 + chunk * 2] = S;
    gpart[bg * 16 + chunk * 2 + 1] = Q;
  }
}

// ---------------- GroupNorm pass 2: normalize + transpose to h_t[B,S,C] bf16 ----------------
__global__ __launch_bounds__(256) void gn_apply_t(
    const float* __restrict__ x, const float* __restrict__ gpart,
    const float* __restrict__ scale, const float* __restrict__ bias,
    unsigned short* __restrict__ h_t) {
  int bid = blockIdx.x;
  int bg = bid >> 4, st = bid & 15;
  int b = bg >> 3, g = bg & 7;
  float S = 0.f, Q = 0.f;
  #pragma unroll
  for (int i = 0; i < 8; ++i) {
    S += gpart[bg * 16 + i * 2];
    Q += gpart[bg * 16 + i * 2 + 1];
  }
  float mean = S / 65536.f;
  float var = Q / 65536.f - mean * mean;
  float inv = rsqrtf(var + EPS_GN);

  int tid = threadIdx.x;
  int sl = tid >> 2;
  int cq = (tid & 3) * 16;
  float sA[16], sB[16];
  #pragma unroll
  for (int u = 0; u < 16; ++u) {
    float scv = scale[g * 64 + cq + u];
    sA[u] = inv * scv;
    sB[u] = bias[g * 64 + cq + u] - mean * inv * scv;
  }

  const float* xp = x + ((size_t)b * C_ + (size_t)g * 64) * S_;
  __shared__ float tile[64][65];
  #pragma unroll
  for (int it = 0; it < 16; ++it) {
    int lin = it * 256 + tid;
    int c = lin >> 6, s = lin & 63;
    tile[c][s] = xp[(size_t)c * S_ + st * 64 + s];
  }
  __syncthreads();
  unsigned short vals[16];
  #pragma unroll
  for (int u = 0; u < 16; ++u)
    vals[u] = f2bf_fast(tile[cq + u][sl] * sA[u] + sB[u]);
  unsigned short* dst = h_t + ((size_t)b * S_ + st * 64 + sl) * C_ + g * 64 + cq;
  ushort8 lo, hi;
  #pragma unroll
  for (int u = 0; u < 8; ++u) { lo[u] = vals[u]; hi[u] = vals[u + 8]; }
  *(ushort8*)dst = lo;
  *(ushort8*)(dst + 8) = hi;
}

// ---------------- NT GEMM core, register-prefetch pipelined staging ----------------
// C[MB,NB] = A[MB,512] * B[NB,512]^T ; next k-slab loads issue during MFMA phase.
template<int MB, int NB, int WMG, int WNG>
__device__ __forceinline__ void gemm_nt_core(
    const unsigned short* __restrict__ Ab,
    const unsigned short* __restrict__ Bb,
    unsigned short* ldsA, unsigned short* ldsB,
    f32x4* acc) {
  constexpr int TI = (MB / WMG) / 16;
  constexpr int TJ = (NB / WNG) / 16;
  constexpr int NQA = MB * 4 / 256;          // 16B chunks per thread (A)
  constexpr int NQB = NB * 4 / 256;
  const int K = 512;
  const int tid = threadIdx.x;
  const int w = tid >> 6, lane = tid & 63, quad = lane >> 4, l15 = lane & 15;
  const int wm = (WNG == 1) ? w : ((WMG == 1) ? 0 : (w >> 1));
  const int wn = (WNG == 1) ? 0 : ((WMG == 1) ? w : (w & 1));

  ushort8 apf[NQA], bpf[NQB];
  #pragma unroll
  for (int q = 0; q < NQA; ++q) {
    int c = q * 256 + tid;
    apf[q] = *(const ushort8*)(Ab + (size_t)(c >> 2) * K + (c & 3) * 8);
  }
  #pragma unroll
  for (int q = 0; q < NQB; ++q) {
    int c = q * 256 + tid;
    bpf[q] = *(const ushort8*)(Bb + (size_t)(c >> 2) * K + (c & 3) * 8);
  }

  for (int k0 = 0; k0 < K; k0 += 32) {
    __syncthreads();                         // prior slab consumed
    #pragma unroll
    for (int q = 0; q < NQA; ++q) {
      int c = q * 256 + tid;
      *(ushort8*)(ldsA + c * 8) = apf[q];
    }
    #pragma unroll
    for (int q = 0; q < NQB; ++q) {
      int c = q * 256 + tid;
      *(ushort8*)(ldsB + c * 8) = bpf[q];
    }
    __syncthreads();
    if (k0 + 32 < K) {                       // issue next-slab loads; waited next iter
      #pragma unroll
      for (int q = 0; q < NQA; ++q) {
        int c = q * 256 + tid;
        apf[q] = *(const ushort8*)(Ab + (size_t)(c >> 2) * K + k0 + 32 + (c & 3) * 8);
      }
      #pragma unroll
      for (int q = 0; q < NQB; ++q) {
        int c = q * 256 + tid;
        bpf[q] = *(const ushort8*)(Bb + (size_t)(c >> 2) * K + k0 + 32 + (c & 3) * 8);
      }
    }
    bf16x8 af[TI], bfr[TJ];
    #pragma unroll
    for (int i = 0; i < TI; ++i)
      af[i] = *(const bf16x8*)(ldsA + (wm * (MB / WMG) + i * 16 + l15) * 32 + quad * 8);
    #pragma unroll
    for (int j = 0; j < TJ; ++j)
      bfr[j] = *(const bf16x8*)(ldsB + (wn * (NB / WNG) + j * 16 + l15) * 32 + quad * 8);
    #pragma unroll
    for (int i = 0; i < TI; ++i)
      #pragma unroll
      for (int j = 0; j < TJ; ++j)
        acc[i * TJ + j] = __builtin_amdgcn_mfma_f32_16x16x32_bf16(af[i], bfr[j], acc[i * TJ + j], 0, 0, 0);
  }
}

// ---------------- QKV GEMM: W_bf[1536,512] x h_t[b][1024,512]^T ----------------
__global__ __launch_bounds__(256) void gemm_qkv_mfma(
    const unsigned short* __restrict__ Wbf, const unsigned short* __restrict__ h_t,
    const float* __restrict__ bias,
    unsigned short* __restrict__ Qt, unsigned short* __restrict__ Kt,
    unsigned short* __restrict__ Vt) {
  __shared__ __align__(16) unsigned short ldsA[128 * 32];
  __shared__ __align__(16) unsigned short ldsB[128 * 32];
  int b = blockIdx.z;
  int bm = blockIdx.y * 128, bn = blockIdx.x * 128;
  f32x4 acc[16];
  #pragma unroll
  for (int t = 0; t < 16; ++t) acc[t] = (f32x4){0.f, 0.f, 0.f, 0.f};
  gemm_nt_core<128, 128, 2, 2>(Wbf + (size_t)bm * 512,
                               h_t + ((size_t)b * S_ + bn) * 512, ldsA, ldsB, acc);
  int tid = threadIdx.x, w = tid >> 6, lane = tid & 63, quad = lane >> 4, l15 = lane & 15;
  int wm = w >> 1, wn = w & 1;
  int tensor = bm >> 9;
  float qscale = (tensor == 0) ? 0.125f * LOG2E : 1.0f;
  #pragma unroll
  for (int i = 0; i < 4; ++i) {
    #pragma unroll
    for (int j = 0; j < 4; ++j) {
      int m0 = bm + wm * 64 + i * 16 + quad * 4;
      int ng = bn + wn * 64 + j * 16 + l15;
      f32x4 v = acc[i * 4 + j];
      if (tensor < 2) {
        int head = (m0 >> 6) & 7, d0 = m0 & 63;
        ushort4_t pk;
        #pragma unroll
        for (int r = 0; r < 4; ++r) pk[r] = f2bf((v[r] + bias[m0 + r]) * qscale);
        unsigned short* dst = (tensor ? Kt : Qt) +
            (((size_t)(b * 8 + head) * S_ + ng) * 64 + d0);
        *(ushort4_t*)dst = pk;
      } else {
        #pragma unroll
        for (int r = 0; r < 4; ++r)
          Vt[(size_t)b * (C_ * S_) + (size_t)(m0 - 1024 + r) * S_ + ng] = f2bf(v[r] + bias[m0 + r]);
      }
    }
  }
}

// ---------------- Flash attention: transposed scores, 2 q-groups/wave, reg-prefetched K/V ----------------
// grid 512: bid = sblk*64 + (b*8+n); 4 waves x 32 q-rows (2 groups of 16)
__global__ __launch_bounds__(256) void attn_mfma(
    const unsigned short* __restrict__ Qt,   // [B][NH][S][HD] (pre-scaled, incl log2e)
    const unsigned short* __restrict__ Kt,
    const unsigned short* __restrict__ Vt,   // [B][C][S]
    unsigned short* __restrict__ hflat_bf) { // [B][S][C] bf16
  int tid = threadIdx.x, wave = tid >> 6, lane = tid & 63;
  int quad = lane >> 4, l15 = lane & 15;
  int bid = blockIdx.x;
  int bn = bid & 63, sblk = bid >> 6, b = bn >> 3, n = bn & 7;
  int s0w = sblk * 128 + wave * 32;

  __shared__ unsigned short k_lds[64][72];
  __shared__ unsigned short v_lds[64][72];
  __shared__ unsigned short p_lds[4][2][16][72];  // [wave][group][s][t], A-layout

  const unsigned short* Kb = Kt + ((size_t)(b * 8 + n)) * S_ * 64;
  const unsigned short* Vb = Vt + ((size_t)b * C_ + n * 64) * S_;

  bf16x8 qa[2][2];
  #pragma unroll
  for (int g = 0; g < 2; ++g) {
    const unsigned short* Qb = Qt + (((size_t)(b * 8 + n)) * S_ + s0w + g * 16 + l15) * 64;
    qa[g][0] = *(const bf16x8*)(Qb + quad * 8);
    qa[g][1] = *(const bf16x8*)(Qb + 32 + quad * 8);
  }

  bf16x8 ones;
  #pragma unroll
  for (int j = 0; j < 8; ++j) ones[j] = (short)0x3F80;

  f32x4 o_acc[2][4];
  f32x4 l_acc[2];
  #pragma unroll
  for (int g = 0; g < 2; ++g) {
    l_acc[g] = (f32x4){0.f, 0.f, 0.f, 0.f};
    #pragma unroll
    for (int dc = 0; dc < 4; ++dc) o_acc[g][dc] = (f32x4){0.f, 0.f, 0.f, 0.f};
  }

  int row0 = tid >> 3, c80 = (tid & 7) * 8;
  int row1 = (tid + 256) >> 3, c81 = c80;

  ushort8 kreg[2], vreg[2];
  kreg[0] = *(const ushort8*)(Kb + (size_t)row0 * 64 + c80);
  kreg[1] = *(const ushort8*)(Kb + (size_t)row1 * 64 + c81);
  vreg[0] = *(const ushort8*)(Vb + (size_t)row0 * S_ + c80);
  vreg[1] = *(const ushort8*)(Vb + (size_t)row1 * S_ + c81);

  for (int t0 = 0; t0 < S_; t0 += 64) {
    __syncthreads();
    *(ushort8*)&k_lds[row0][c80] = kreg[0];
    *(ushort8*)&k_lds[row1][c81] = kreg[1];
    *(ushort8*)&v_lds[row0][c80] = vreg[0];
    *(ushort8*)&v_lds[row1][c81] = vreg[1];
    __syncthreads();
    if (t0 + 64 < S_) {
      int t1 = t0 + 64;
      kreg[0] = *(const ushort8*)(Kb + (size_t)(t1 + row0) * 64 + c80);
      kreg[1] = *(const ushort8*)(Kb + (size_t)(t1 + row1) * 64 + c81);
      vreg[0] = *(const ushort8*)(Vb + (size_t)row0 * S_ + t1 + c80);
      vreg[1] = *(const ushort8*)(Vb + (size_t)row1 * S_ + t1 + c81);
    }

    // Transposed scores: St[t][s] = sum_d K[t][d] Q[s][d]
    f32x4 sc[2][4];
    #pragma unroll
    for (int tc = 0; tc < 4; ++tc) {
      bf16x8 kb0 = *(const bf16x8*)&k_lds[tc * 16 + l15][quad * 8];
      bf16x8 kb1 = *(const bf16x8*)&k_lds[tc * 16 + l15][32 + quad * 8];
      #pragma unroll
      for (int g = 0; g < 2; ++g) {
        f32x4 c = {0.f, 0.f, 0.f, 0.f};
        c = __builtin_amdgcn_mfma_f32_16x16x32_bf16(kb0, qa[g][0], c, 0, 0, 0);
        sc[g][tc] = __builtin_amdgcn_mfma_f32_16x16x32_bf16(kb1, qa[g][1], c, 0, 0, 0);
      }
    }

    // exp -> P[s][t] in LDS via contiguous b64 writes
    #pragma unroll
    for (int g = 0; g < 2; ++g)
      #pragma unroll
      for (int tc = 0; tc < 4; ++tc) {
        ushort4_t p4;
        #pragma unroll
        for (int r = 0; r < 4; ++r) p4[r] = f2bf_fast(exp2_raw(sc[g][tc][r]));
        *(ushort4_t*)&p_lds[wave][g][l15][tc * 16 + quad * 4] = p4;
      }

    bf16x8 pa[2][2];
    #pragma unroll
    for (int g = 0; g < 2; ++g) {
      pa[g][0] = *(const bf16x8*)&p_lds[wave][g][l15][quad * 8];
      pa[g][1] = *(const bf16x8*)&p_lds[wave][g][l15][32 + quad * 8];
      l_acc[g] = __builtin_amdgcn_mfma_f32_16x16x32_bf16(pa[g][0], ones, l_acc[g], 0, 0, 0);
      l_acc[g] = __builtin_amdgcn_mfma_f32_16x16x32_bf16(pa[g][1], ones, l_acc[g], 0, 0, 0);
    }
    #pragma unroll
    for (int dc = 0; dc < 4; ++dc) {
      bf16x8 vb0 = *(const bf16x8*)&v_lds[dc * 16 + l15][quad * 8];
      bf16x8 vb1 = *(const bf16x8*)&v_lds[dc * 16 + l15][32 + quad * 8];
      #pragma unroll
      for (int g = 0; g < 2; ++g) {
        o_acc[g][dc] = __builtin_amdgcn_mfma_f32_16x16x32_bf16(pa[g][0], vb0, o_acc[g][dc], 0, 0, 0);
        o_acc[g][dc] = __builtin_amdgcn_mfma_f32_16x16x32_bf16(pa[g][1], vb1, o_acc[g][dc], 0, 0, 0);
      }
    }
  }

  #pragma unroll
  for (int g = 0; g < 2; ++g) {
    float inv_l[4];
    #pragma unroll
    for (int r = 0; r < 4; ++r) inv_l[r] = 1.f / l_acc[g][r];
    #pragma unroll
    for (int dc = 0; dc < 4; ++dc) {
      #pragma unroll
      for (int r = 0; r < 4; ++r) {
        int s = s0w + g * 16 + quad * 4 + r;
        size_t idx = ((size_t)b * S_ + s) * C_ + n * 64 + dc * 16 + l15;
        hflat_bf[idx] = f2bf_fast(o_acc[g][dc][r] * inv_l[r]);
      }
    }
  }
}

// ---------------- Fused INL x3 + proj + residual: DMA-pipelined depth-2, LDS-optimized ----------------
// Round-12 diagnosis: swizzle fixed bank conflicts (4.2M->1.05M) but dur ~41us => the
// residual wall is the SINGLE-ROUND DMA slack: slab g+1 issued at round g must COMPLETE
// within one ~600cyc round (vmcnt(4) at round g+1); DMA completion latency ~600-900cyc
// leaves a per-round stall, with only 2 waves/SIMD to hide it.
// Fix: TRIPLE-BUFFER -> prefetch distance 2 rounds (~1200cyc slack). Round g:
// lgkmcnt(0) -> issue slab g+2 into buf[(g+2)%3] -> vmcnt(8) (slabs g+1,g+2 in flight,
// slab g landed). Per-wave self-contained quarters: no barriers in main loop.
__global__ __launch_bounds__(512, 2) void inl_proj_chain(
    const unsigned short* __restrict__ hbf,   // [B*S][512] bf16 (attn out rows)
    const unsigned short* __restrict__ Wi2,   // inl W, swizzled slab-interleaved
    const unsigned short* __restrict__ Wp2,   // proj W, swizzled slab-interleaved
    const float* __restrict__ ib, const float* __restrict__ pb,
    const float* __restrict__ x, float* __restrict__ Out) {
  __shared__ __align__(16) unsigned short h_lds[32][520];   // 33.3KB
  __shared__ __align__(16) unsigned short w_lds[3][16384];  // 96KB triple-buf, [512 o][32 k]

  int tid = threadIdx.x;
  int wave = tid >> 6, lane = tid & 63, quad = lane >> 4, l15 = lane & 15;
  int wo = wave * 64;                        // this wave's 64 output channels = its W rows
  int bid = blockIdx.x;
  int b = bid >> 5, s0 = (bid & 31) * 32;    // 32 blocks per batch image

  const unsigned short* hsrc = hbf + (size_t)bid * 16384;
  ushort8 hv0 = *(const ushort8*)(hsrc + (size_t)tid * 8);
  ushort8 hv1 = *(const ushort8*)(hsrc + (size_t)(512 + tid) * 8);
  ushort8 hv2 = *(const ushort8*)(hsrc + (size_t)(1024 + tid) * 8);
  ushort8 hv3 = *(const ushort8*)(hsrc + (size_t)(1536 + tid) * 8);

  float bi0 = ib[wo + l15],      bi1 = ib[wo + 16 + l15];
  float bi2 = ib[wo + 32 + l15], bi3 = ib[wo + 48 + l15];
  float bp0 = pb[wo + l15],      bp1 = pb[wo + 16 + l15];
  float bp2 = pb[wo + 32 + l15], bp3 = pb[wo + 48 + l15];

  *(ushort8*)&h_lds[tid >> 6][(tid & 63) * 8] = hv0;
  { int lin = 512 + tid;  *(ushort8*)&h_lds[lin >> 6][(lin & 63) * 8] = hv1; }
  { int lin = 1024 + tid; *(ushort8*)&h_lds[lin >> 6][(lin & 63) * 8] = hv2; }
  { int lin = 1536 + tid; *(ushort8*)&h_lds[lin >> 6][(lin & 63) * 8] = hv3; }

  f32x4 acc00 = {0.f,0.f,0.f,0.f}, acc01 = {0.f,0.f,0.f,0.f};
  f32x4 acc02 = {0.f,0.f,0.f,0.f}, acc03 = {0.f,0.f,0.f,0.f};
  f32x4 acc10 = {0.f,0.f,0.f,0.f}, acc11 = {0.f,0.f,0.f,0.f};
  f32x4 acc12 = {0.f,0.f,0.f,0.f}, acc13 = {0.f,0.f,0.f,0.f};

  const int o0 = wo + l15,      o1 = wo + 16 + l15;
  const int o2 = wo + 32 + l15, o3 = wo + 48 + l15;
  const int wofs = wave * 2048;              // 64 rows x 32 shorts
  const int lofs = lane * 8;                 // lane's 16B within a 1KB DMA call
  const int wcol = (quad ^ ((l15 >> 1) & 3)) * 8;   // chunk-XOR read swizzle (matches prep)

  __syncthreads();                           // h_lds ready (drains h loads; no DMA yet)

#define ISSUE_(base, slab, buf) { \
    const unsigned short* ws_ = (base) + (slab) * 16384 + wofs; \
    gload_lds16(ws_ + lofs, &w_lds[buf][wofs]); \
    gload_lds16(ws_ + 512 + lofs, &w_lds[buf][wofs + 512]); \
    gload_lds16(ws_ + 1024 + lofs, &w_lds[buf][wofs + 1024]); \
    gload_lds16(ws_ + 1536 + lofs, &w_lds[buf][wofs + 1536]); }

  ISSUE_(Wi2, 0, 0);                         // prologue: slabs 0,1 in flight
  ISSUE_(Wi2, 1, 1);

  #pragma unroll
  for (int step = 0; step < 4; ++step) {
    #pragma unroll
    for (int s = 0; s < 16; ++s) {
      const int g = step * 16 + s;
      const int cur = g % 3;
      asm volatile("s_waitcnt lgkmcnt(0)" ::: "memory");  // own round g-3..g-1 reads done
      if (g + 2 < 64) {
        const unsigned short* nb_ = ((g + 2) < 48) ? Wi2 : Wp2;
        ISSUE_(nb_, (g + 2) & 15, (g + 2) % 3);
        asm volatile("s_waitcnt vmcnt(8)" ::: "memory");  // slab g landed; g+1,g+2 in flight
      } else if (g + 1 < 64) {
        asm volatile("s_waitcnt vmcnt(4)" ::: "memory");  // slab g landed; g+1 in flight
      } else {
        asm volatile("s_waitcnt vmcnt(0)" ::: "memory");
      }

      const int kb = s * 32 + quad * 8;
      bf16x8 a0 = *(const bf16x8*)&h_lds[l15][kb];
      bf16x8 a1 = *(const bf16x8*)&h_lds[16 + l15][kb];
      bf16x8 w0 = *(const bf16x8*)&w_lds[cur][o0 * 32 + wcol];
      bf16x8 w1 = *(const bf16x8*)&w_lds[cur][o1 * 32 + wcol];
      bf16x8 w2 = *(const bf16x8*)&w_lds[cur][o2 * 32 + wcol];
      bf16x8 w3 = *(const bf16x8*)&w_lds[cur][o3 * 32 + wcol];
      acc00 = __builtin_amdgcn_mfma_f32_16x16x32_bf16(a0, w0, acc00, 0, 0, 0);
      acc10 = __builtin_amdgcn_mfma_f32_16x16x32_bf16(a1, w0, acc10, 0, 0, 0);
      acc01 = __builtin_amdgcn_mfma_f32_16x16x32_bf16(a0, w1, acc01, 0, 0, 0);
      acc11 = __builtin_amdgcn_mfma_f32_16x16x32_bf16(a1, w1, acc11, 0, 0, 0);
      acc02 = __builtin_amdgcn_mfma_f32_16x16x32_bf16(a0, w2, acc02, 0, 0, 0);
      acc12 = __builtin_amdgcn_mfma_f32_16x16x32_bf16(a1, w2, acc12, 0, 0, 0);
      acc03 = __builtin_amdgcn_mfma_f32_16x16x32_bf16(a0, w3, acc03, 0, 0, 0);
      acc13 = __builtin_amdgcn_mfma_f32_16x16x32_bf16(a1, w3, acc13, 0, 0, 0);
    }

    if (step < 3) {                          // end of INL step: in-LDS tanh update
      __syncthreads();
      #pragma unroll
      for (int r = 0; r < 4; ++r) {
        int sa = quad * 4 + r, sb = 16 + quad * 4 + r;
        h_lds[sa][o0] = f2bf_fast(bf2f(h_lds[sa][o0]) + DT_STEP * fast_tanh(acc00[r] + bi0));
        h_lds[sa][o1] = f2bf_fast(bf2f(h_lds[sa][o1]) + DT_STEP * fast_tanh(acc01[r] + bi1));
        h_lds[sa][o2] = f2bf_fast(bf2f(h_lds[sa][o2]) + DT_STEP * fast_tanh(acc02[r] + bi2));
        h_lds[sa][o3] = f2bf_fast(bf2f(h_lds[sa][o3]) + DT_STEP * fast_tanh(acc03[r] + bi3));
        h_lds[sb][o0] = f2bf_fast(bf2f(h_lds[sb][o0]) + DT_STEP * fast_tanh(acc10[r] + bi0));
        h_lds[sb][o1] = f2bf_fast(bf2f(h_lds[sb][o1]) + DT_STEP * fast_tanh(acc11[r] + bi1));
        h_lds[sb][o2] = f2bf_fast(bf2f(h_lds[sb][o2]) + DT_STEP * fast_tanh(acc12[r] + bi2));
        h_lds[sb][o3] = f2bf_fast(bf2f(h_lds[sb][o3]) + DT_STEP * fast_tanh(acc13[r] + bi3));
      }
      acc00 = (f32x4){0.f,0.f,0.f,0.f}; acc01 = (f32x4){0.f,0.f,0.f,0.f};
      acc02 = (f32x4){0.f,0.f,0.f,0.f}; acc03 = (f32x4){0.f,0.f,0.f,0.f};
      acc10 = (f32x4){0.f,0.f,0.f,0.f}; acc11 = (f32x4){0.f,0.f,0.f,0.f};
      acc12 = (f32x4){0.f,0.f,0.f,0.f}; acc13 = (f32x4){0.f,0.f,0.f,0.f};
      __syncthreads();
    }
  }

  // proj epilogue: Out[b][o][s0..] = x + pb + acc ; 4 consecutive s per reg quad -> f32x4
#define EPI_(oj, bpj, aI0, aI1) { \
    size_t base_ = (((size_t)b * 512 + (oj)) << 10) + (size_t)(s0 + quad * 4); \
    f32x4 xv_, ov_; \
    xv_ = *(const f32x4*)(x + base_); \
    _Pragma("unroll") \
    for (int r = 0; r < 4; ++r) ov_[r] = xv_[r] + (bpj) + aI0[r]; \
    *(f32x4*)(Out + base_) = ov_; \
    xv_ = *(const f32x4*)(x + base_ + 16); \
    _Pragma("unroll") \
    for (int r = 0; r < 4; ++r) ov_[r] = xv_[r] + (bpj) + aI1[r]; \
    *(f32x4*)(Out + base_ + 16) = ov_; }

  EPI_(o0, bp0, acc00, acc10);
  EPI_(o1, bp1, acc01, acc11);
  EPI_(o2, bp2, acc02, acc12);
  EPI_(o3, bp3, acc03, acc13);
#undef EPI_
#undef ISSUE_
}

extern "C" void kernel_launch(void* const* d_in, const int* in_sizes, int n_in,
                              void* d_out, int out_size, void* d_ws, size_t ws_size,
                              hipStream_t stream) {
  const float* x        = (const float*)d_in[0];
  const float* gn_scale = (const float*)d_in[1];
  const float* gn_bias  = (const float*)d_in[2];
  const float* qkv_w    = (const float*)d_in[3];
  const float* qkv_b    = (const float*)d_in[4];
  const float* proj_w   = (const float*)d_in[5];
  const float* proj_b   = (const float*)d_in[6];
  const float* inl_w    = (const float*)d_in[7];
  const float* inl_b    = (const float*)d_in[8];
  float* out = (float*)d_out;
  float* ws = (float*)d_ws;

  unsigned short* Qt  = (unsigned short*)(ws + 8388608);
  unsigned short* Kt  = (unsigned short*)(ws + 10485760);
  unsigned short* Vt  = (unsigned short*)(ws + 12582912);
  unsigned short* h_t = (unsigned short*)(ws + 14680064);
  unsigned short* Abf = (unsigned short*)(ws + 16777216);
  float* gpart = ws + 18874368;
  unsigned short* qkvw_bf  = (unsigned short*)(ws + 18878464);
  unsigned short* inlw_bf  = qkvw_bf + 786432;
  unsigned short* projw_bf = inlw_bf + 262144;

  prep_kernel<<<1152, 256, 0, stream>>>(qkv_w, inl_w, proj_w, qkvw_bf, inlw_bf, projw_bf, x, gpart);
  gn_apply_t<<<1024, 256, 0, stream>>>(x, gpart, gn_scale, gn_bias, h_t);
  gemm_qkv_mfma<<<dim3(8, 12, 8), 256, 0, stream>>>(qkvw_bf, h_t, qkv_b, Qt, Kt, Vt);
  attn_mfma<<<512, 256, 0, stream>>>(Qt, Kt, Vt, Abf);
  inl_proj_chain<<<256, 512, 0, stream>>>(Abf, inlw_bf, projw_bf, inl_b, proj_b, x, out);
}